// Round 2
// baseline (1130.519 us; speedup 1.0000x reference)
//
#include <hip/hip_runtime.h>
#include <hip/hip_bf16.h>

typedef _Float16 f16x8 __attribute__((ext_vector_type(8)));
typedef _Float16 f16x4 __attribute__((ext_vector_type(4)));
typedef float    f32x4 __attribute__((ext_vector_type(4)));

#define B_   64
#define N_   512
#define D_   1024
#define HROWS (B_ * N_)          // 32768
#define EPS_ 1e-5f

__device__ __forceinline__ void gload_lds16(const _Float16* g, _Float16* l) {
    __builtin_amdgcn_global_load_lds(
        (const __attribute__((address_space(1))) void*)g,
        (__attribute__((address_space(3))) void*)l, 16, 0, 0);
}

// ---------------- elementwise / prep kernels ----------------

__global__ void k_cvt_f16(const float* __restrict__ in, _Float16* __restrict__ out, int n4) {
    int i = blockIdx.x * blockDim.x + threadIdx.x;
    int stride = gridDim.x * blockDim.x;
    const float4* in4 = (const float4*)in;
    for (; i < n4; i += stride) {
        float4 v = in4[i];
        f16x4 o;
        o[0] = (_Float16)v.x; o[1] = (_Float16)v.y;
        o[2] = (_Float16)v.z; o[3] = (_Float16)v.w;
        *(f16x4*)(out + (size_t)i * 4) = o;
    }
}

// W [1024][1024] fp32 -> Wt [1024][1024] f16 (transposed)
__global__ void k_transpose_w(const float* __restrict__ in, _Float16* __restrict__ out) {
    __shared__ float tile[32][33];
    int bx = blockIdx.x * 32;   // col base of in == row base of out
    int by = blockIdx.y * 32;   // row base of in
    int tx = threadIdx.x, ty = threadIdx.y;
    #pragma unroll
    for (int r = 0; r < 32; r += 8)
        tile[ty + r][tx] = in[(size_t)(by + ty + r) * 1024 + bx + tx];
    __syncthreads();
    #pragma unroll
    for (int r = 0; r < 32; r += 8)
        out[(size_t)(bx + ty + r) * 1024 + by + tx] = (_Float16)tile[tx][ty + r];
}

// ---------------- BN stats / normalize ----------------

__global__ void k_bnstats(const float* __restrict__ t, const float* __restrict__ gamma,
                          const float* __restrict__ beta, float* __restrict__ scale,
                          float* __restrict__ shift) {
    const int n = blockIdx.x, tid = threadIdx.x;
    float s = 0.f, s2 = 0.f;
    const float* base = t + (size_t)n * 1024 + tid * 4;
    for (int b = 0; b < 64; ++b) {
        float4 v = *(const float4*)(base + (size_t)b * 512 * 1024);
        s  += v.x + v.y + v.z + v.w;
        s2 += v.x * v.x + v.y * v.y + v.z * v.z + v.w * v.w;
    }
    #pragma unroll
    for (int o = 32; o > 0; o >>= 1) { s += __shfl_down(s, o); s2 += __shfl_down(s2, o); }
    __shared__ float rs_[4], rs2_[4];
    int lane = tid & 63, w = tid >> 6;
    if (lane == 0) { rs_[w] = s; rs2_[w] = s2; }
    __syncthreads();
    if (tid == 0) {
        float S  = rs_[0] + rs_[1] + rs_[2] + rs_[3];
        float S2 = rs2_[0] + rs2_[1] + rs2_[2] + rs2_[3];
        float mean = S * (1.f / 65536.f);
        float var  = S2 * (1.f / 65536.f) - mean * mean;
        float r = rsqrtf(var + EPS_);
        float sc = gamma[n] * r;
        scale[n] = sc;
        shift[n] = beta[n] - mean * sc;
    }
}

// per (b,n) row: normalize + leaky, row-mean, write theta f16 and theta_c f16
__global__ void k_bnorm(const float* __restrict__ t, const float* __restrict__ scale,
                        const float* __restrict__ shift, _Float16* __restrict__ theta,
                        _Float16* __restrict__ thetac) {
    const int row = blockIdx.x, tid = threadIdx.x;
    const int n = row & 511;
    const float sc = scale[n], sh = shift[n];
    float4 v = *(const float4*)(t + (size_t)row * 1024 + tid * 4);
    float a0 = fmaf(v.x, sc, sh); a0 = a0 >= 0.f ? a0 : 0.01f * a0;
    float a1 = fmaf(v.y, sc, sh); a1 = a1 >= 0.f ? a1 : 0.01f * a1;
    float a2 = fmaf(v.z, sc, sh); a2 = a2 >= 0.f ? a2 : 0.01f * a2;
    float a3 = fmaf(v.w, sc, sh); a3 = a3 >= 0.f ? a3 : 0.01f * a3;
    float s = a0 + a1 + a2 + a3;
    #pragma unroll
    for (int o = 32; o > 0; o >>= 1) s += __shfl_down(s, o);
    __shared__ float red[4];
    int lane = tid & 63, w = tid >> 6;
    if (lane == 0) red[w] = s;
    __syncthreads();
    const float mean = (red[0] + red[1] + red[2] + red[3]) * (1.f / 1024.f);
    f16x4 th, tc;
    th[0] = (_Float16)a0; th[1] = (_Float16)a1; th[2] = (_Float16)a2; th[3] = (_Float16)a3;
    tc[0] = (_Float16)(a0 - mean); tc[1] = (_Float16)(a1 - mean);
    tc[2] = (_Float16)(a2 - mean); tc[3] = (_Float16)(a3 - mean);
    *(f16x4*)(theta  + (size_t)row * 1024 + tid * 4) = th;
    *(f16x4*)(thetac + (size_t)row * 1024 + tid * 4) = tc;
}

// ---------------- global softmax (per batch, over 512*512) ----------------

__device__ __forceinline__ unsigned f2key(float f) {
    unsigned u = __float_as_uint(f);
    return (u & 0x80000000u) ? ~u : (u | 0x80000000u);
}
__device__ __forceinline__ float key2f(unsigned k) {
    unsigned u = (k & 0x80000000u) ? (k & 0x7fffffffu) : ~k;
    return __uint_as_float(u);
}

__global__ void k_smax_init(unsigned* __restrict__ mkey, float* __restrict__ ssum) {
    int i = threadIdx.x;
    if (i < 64) { mkey[i] = 0u; ssum[i] = 0.f; }
}

__global__ void k_smax_max(const float* __restrict__ sigma, unsigned* __restrict__ mkey) {
    const int b = blockIdx.y, tid = threadIdx.x;
    float4 v = *(const float4*)(sigma + (size_t)b * 262144 + blockIdx.x * 1024 + tid * 4);
    float m = fmaxf(fmaxf(v.x, v.y), fmaxf(v.z, v.w));
    #pragma unroll
    for (int o = 32; o > 0; o >>= 1) m = fmaxf(m, __shfl_down(m, o));
    __shared__ float red[4];
    int lane = tid & 63, w = tid >> 6;
    if (lane == 0) red[w] = m;
    __syncthreads();
    if (tid == 0)
        atomicMax(mkey + b, f2key(fmaxf(fmaxf(red[0], red[1]), fmaxf(red[2], red[3]))));
}

__global__ void k_smax_sum(const float* __restrict__ sigma, const unsigned* __restrict__ mkey,
                           float* __restrict__ ssum) {
    const int b = blockIdx.y, tid = threadIdx.x;
    const float mx = key2f(mkey[b]);
    float4 v = *(const float4*)(sigma + (size_t)b * 262144 + blockIdx.x * 1024 + tid * 4);
    float s = __expf(v.x - mx) + __expf(v.y - mx) + __expf(v.z - mx) + __expf(v.w - mx);
    #pragma unroll
    for (int o = 32; o > 0; o >>= 1) s += __shfl_down(s, o);
    __shared__ float red[4];
    int lane = tid & 63, w = tid >> 6;
    if (lane == 0) red[w] = s;
    __syncthreads();
    if (tid == 0) atomicAdd(ssum + b, red[0] + red[1] + red[2] + red[3]);
}

__global__ void k_smax_write(const float* __restrict__ sigma, const unsigned* __restrict__ mkey,
                             _Float16* __restrict__ att) {
    const int b = blockIdx.y, tid = threadIdx.x;
    const float mx = key2f(mkey[b]);
    size_t ofs = (size_t)b * 262144 + blockIdx.x * 1024 + tid * 4;
    float4 v = *(const float4*)(sigma + ofs);
    f16x4 o;
    o[0] = (_Float16)__expf(v.x - mx); o[1] = (_Float16)__expf(v.y - mx);
    o[2] = (_Float16)__expf(v.z - mx); o[3] = (_Float16)__expf(v.w - mx);
    *(f16x4*)(att + ofs) = o;
}

// ---------------- shared NT GEMM: C = A * B^T (+epilogue per MODE) ----------------
// MODE 0: t   = xb @ W1t^T + b1          fp32 out, M=32768 N=1024 K=1024
// MODE 1: sig = theta_c @ theta^T / 32768 fp32 out, per batch M=N=512 K=1024
// MODE 2: g_t[b][h][m] = (xb @ W2t^T + b2)^T  f16 out, M=32768 N=1024 K=1024
// MODE 3: ag  = att @ g_t^T * (1/ssum[b])     f16 out, per batch M=512 N=1024 K=512
// MODE 4: out = ag@W3 + xb@W4 + b3 + b4       fp32 out, M=32768 N=1024 K=2048 (concat)
//
// Staging: global_load_lds width=16 (linear LDS dest), LDS logical layout is
// [kg][row][8] f16 chunks (chunk L holds row=L&127, kg=L>>7) so that fragment
// ds_read_b128 hits 16 consecutive chunks per 16-lane group -> conflict-free.

template <int MODE>
__global__ __launch_bounds__(256) void k_gemm(
    const _Float16* __restrict__ A0, const _Float16* __restrict__ A1,
    const _Float16* __restrict__ B0, const _Float16* __restrict__ B1,
    const float* __restrict__ bias0, const float* __restrict__ bias1,
    const float* __restrict__ sumptr, void* __restrict__ outp) {

    constexpr int BK = 32;
    __shared__ _Float16 Al[4096];   // 512 chunks of 8 f16
    __shared__ _Float16 Bl[4096];

    const int tid = threadIdx.x, lane = tid & 63, w = tid >> 6;
    const int wm = w >> 1, wn = w & 1;

    int bm, bn, bz = 0;
    if constexpr (MODE == 0 || MODE == 2 || MODE == 4) {
        // XCD-aware swizzle: nwg = 2048, divisible by 8 -> bijective
        const int nwg = gridDim.x;
        const int bid = blockIdx.x;
        const int swz = (bid & 7) * (nwg >> 3) + (bid >> 3);
        bm = swz >> 3;      // 256 M-blocks, contiguous within an XCD
        bn = swz & 7;       // 8 N-blocks
    } else {
        bm = blockIdx.x; bn = blockIdx.y; bz = blockIdx.z;
    }

    int K_, LDA, LDB;
    size_t aOff, bOff;
    if constexpr (MODE == 0 || MODE == 2 || MODE == 4) {
        K_ = (MODE == 4) ? 2048 : 1024; LDA = 1024; LDB = 1024;
        aOff = (size_t)bm * 128 * 1024;
        bOff = (size_t)bn * 128 * 1024;
    } else if constexpr (MODE == 1) {
        K_ = 1024; LDA = 1024; LDB = 1024;
        aOff = ((size_t)bz * 512 + bm * 128) * 1024;
        bOff = ((size_t)bz * 512 + bn * 128) * 1024;
    } else { // MODE 3
        K_ = 512; LDA = 512; LDB = 512;
        aOff = (size_t)bz * 262144 + (size_t)bm * 128 * 512;
        bOff = (size_t)bz * 524288 + (size_t)bn * 128 * 512;
    }

    float oscale = 1.f;
    if constexpr (MODE == 3) oscale = 1.f / sumptr[bz];

    // staging chunk ids: call 0 -> chunk tid, call 1 -> chunk 256+tid
    const int ar0 = tid & 127, ak0 = tid >> 7;              // chunk tid
    const int ar1 = (256 + tid) & 127, ak1 = (256 + tid) >> 7;
    _Float16* lA0 = &Al[(w * 64) * 8];          // wave-uniform bases
    _Float16* lA1 = &Al[(256 + w * 64) * 8];
    _Float16* lB0 = &Bl[(w * 64) * 8];
    _Float16* lB1 = &Bl[(256 + w * 64) * 8];

    const int lr = lane & 15, kg = lane >> 4;

    f32x4 acc[4][4] = {};

    for (int k0 = 0; k0 < K_; k0 += BK) {
        const _Float16* As; const _Float16* Bs; int kk = k0;
        if constexpr (MODE == 4) {
            if (k0 < 1024) { As = A0; Bs = B0; }
            else           { As = A1; Bs = B1; kk = k0 - 1024; }
        } else { As = A0; Bs = B0; }

        gload_lds16(As + aOff + (size_t)ar0 * LDA + kk + ak0 * 8, lA0);
        gload_lds16(As + aOff + (size_t)ar1 * LDA + kk + ak1 * 8, lA1);
        gload_lds16(Bs + bOff + (size_t)ar0 * LDB + kk + ak0 * 8, lB0);
        gload_lds16(Bs + bOff + (size_t)ar1 * LDB + kk + ak1 * 8, lB1);
        __syncthreads();   // compiler drains vmcnt before barrier

        f16x8 af[4], bf[4];
        #pragma unroll
        for (int m = 0; m < 4; m++)
            af[m] = *(const f16x8*)&Al[(kg * 128 + wm * 64 + m * 16 + lr) * 8];
        #pragma unroll
        for (int n = 0; n < 4; n++)
            bf[n] = *(const f16x8*)&Bl[(kg * 128 + wn * 64 + n * 16 + lr) * 8];
        #pragma unroll
        for (int m = 0; m < 4; m++)
            #pragma unroll
            for (int n = 0; n < 4; n++)
                acc[m][n] = __builtin_amdgcn_mfma_f32_16x16x32_f16(af[m], bf[n], acc[m][n], 0, 0, 0);
        __syncthreads();
    }

    // epilogue
    #pragma unroll
    for (int m = 0; m < 4; m++) {
        #pragma unroll
        for (int n = 0; n < 4; n++) {
            const int r0 = wm * 64 + m * 16 + kg * 4;
            const int c  = wn * 64 + n * 16 + lr;
            if constexpr (MODE == 0) {
                float* o = (float*)outp;
                const size_t gr0 = (size_t)bm * 128 + r0;
                const int gc = bn * 128 + c;
                const float bias = bias0[gc];
                #pragma unroll
                for (int i = 0; i < 4; i++) o[(gr0 + i) * 1024 + gc] = acc[m][n][i] + bias;
            } else if constexpr (MODE == 1) {
                float* o = (float*)outp + (size_t)bz * 262144;
                const int gr0 = bm * 128 + r0, gc = bn * 128 + c;
                #pragma unroll
                for (int i = 0; i < 4; i++)
                    o[(size_t)(gr0 + i) * 512 + gc] = acc[m][n][i] * (1.f / 32768.f);
            } else if constexpr (MODE == 2) {
                _Float16* o = (_Float16*)outp;
                const int gr0 = bm * 128 + r0;
                const int gc = bn * 128 + c;
                const int bb = gr0 >> 9, mm = gr0 & 511;
                const float bias = bias0[gc];
                f16x4 pk;
                #pragma unroll
                for (int i = 0; i < 4; i++) pk[i] = (_Float16)(acc[m][n][i] + bias);
                *(f16x4*)(o + ((size_t)bb * 1024 + gc) * 512 + mm) = pk;
            } else if constexpr (MODE == 3) {
                _Float16* o = (_Float16*)outp + (size_t)bz * 524288;
                const int gr0 = bm * 128 + r0, gc = bn * 128 + c;
                #pragma unroll
                for (int i = 0; i < 4; i++)
                    o[(size_t)(gr0 + i) * 1024 + gc] = (_Float16)(acc[m][n][i] * oscale);
            } else { // MODE 4
                float* o = (float*)outp;
                const size_t gr0 = (size_t)bm * 128 + r0;
                const int gc = bn * 128 + c;
                const float bias = bias0[gc] + bias1[gc];
                #pragma unroll
                for (int i = 0; i < 4; i++) o[(gr0 + i) * 1024 + gc] = acc[m][n][i] + bias;
            }
        }
    }
}

// ---------------- launcher ----------------

extern "C" void kernel_launch(void* const* d_in, const int* in_sizes, int n_in,
                              void* d_out, int out_size, void* d_ws, size_t ws_size,
                              hipStream_t stream) {
    (void)in_sizes; (void)n_in; (void)out_size; (void)ws_size;
    const float* x     = (const float*)d_in[0];
    const float* W1    = (const float*)d_in[1];
    const float* b1    = (const float*)d_in[2];
    const float* gamma = (const float*)d_in[3];
    const float* beta  = (const float*)d_in[4];
    const float* W2    = (const float*)d_in[5];
    const float* b2    = (const float*)d_in[6];
    const float* W3    = (const float*)d_in[7];
    const float* b3    = (const float*)d_in[8];
    const float* W4    = (const float*)d_in[9];
    const float* b4    = (const float*)d_in[10];

    char* wsb = (char*)d_ws;
    const size_t MB = 1024 * 1024;
    _Float16* xb   = (_Float16*)(wsb);                    // 64 MB
    _Float16* W1t  = (_Float16*)(wsb + 64 * MB);          // 2 MB
    _Float16* W2t  = (_Float16*)(wsb + 66 * MB);
    _Float16* W3t  = (_Float16*)(wsb + 68 * MB);
    _Float16* W4t  = (_Float16*)(wsb + 70 * MB);
    float*    t    = (float*)(wsb + 72 * MB);             // 128 MB
    float*    sigma= (float*)(wsb + 72 * MB);             // alias: t dead after bnorm
    _Float16* att  = (_Float16*)(wsb + 136 * MB);         // alias: inside t region (32 MB)
    _Float16* theta  = (_Float16*)(wsb + 200 * MB);       // 64 MB
    _Float16* thetac = (_Float16*)(wsb + 264 * MB);       // 64 MB
    _Float16* g_t  = theta;                               // alias: theta dead after sigma gemm
    _Float16* ag   = thetac;                              // alias: theta_c dead after sigma gemm
    float*    scl  = (float*)(wsb + 328 * MB);
    float*    shf  = (float*)(wsb + 328 * MB + 4096);
    unsigned* mkey = (unsigned*)(wsb + 328 * MB + 8192);
    float*    ssum = (float*)(wsb + 328 * MB + 8192 + 256);

    // 1. x -> f16
    k_cvt_f16<<<8192, 256, 0, stream>>>(x, xb, (64 * 512 * 1024 * 4) / 4 / 4);
    // 2. transpose weights -> f16 [out][in]
    dim3 tb(32, 8), tg(32, 32);
    k_transpose_w<<<tg, tb, 0, stream>>>(W1, W1t);
    k_transpose_w<<<tg, tb, 0, stream>>>(W2, W2t);
    k_transpose_w<<<tg, tb, 0, stream>>>(W3, W3t);
    k_transpose_w<<<tg, tb, 0, stream>>>(W4, W4t);
    // 3. t = xb @ W1 + b1 (fp32)
    k_gemm<0><<<2048, 256, 0, stream>>>(xb, nullptr, W1t, nullptr, b1, nullptr, nullptr, t);
    // 4. BN stats
    k_bnstats<<<512, 256, 0, stream>>>(t, gamma, beta, scl, shf);
    // 5. normalize + leaky + row-center -> theta, theta_c
    k_bnorm<<<32768, 256, 0, stream>>>(t, scl, shf, theta, thetac);
    // 6. sigma = theta_c @ theta^T / 32768 (per batch)
    k_gemm<1><<<dim3(4, 4, 64), 256, 0, stream>>>(thetac, nullptr, theta, nullptr, nullptr, nullptr, nullptr, sigma);
    // 7-10. global softmax per batch
    k_smax_init<<<1, 64, 0, stream>>>(mkey, ssum);
    k_smax_max<<<dim3(256, 64), 256, 0, stream>>>(sigma, mkey);
    k_smax_sum<<<dim3(256, 64), 256, 0, stream>>>(sigma, mkey, ssum);
    k_smax_write<<<dim3(256, 64), 256, 0, stream>>>(sigma, mkey, att);
    // 11. g_t[b][h][m] = (xb @ W2 + b2)^T
    k_gemm<2><<<2048, 256, 0, stream>>>(xb, nullptr, W2t, nullptr, b2, nullptr, nullptr, g_t);
    // 12. ag = (att @ g) / ssum (per batch)
    k_gemm<3><<<dim3(4, 8, 64), 256, 0, stream>>>(att, nullptr, g_t, nullptr, nullptr, nullptr, ssum, ag);
    // 13. out = ag @ W3 + xb @ W4 + b3 + b4
    k_gemm<4><<<2048, 256, 0, stream>>>(ag, xb, W3t, W4t, b3, b4, nullptr, d_out);
}

// Round 3
// 913.038 us; speedup vs baseline: 1.2382x; 1.2382x over previous
//
#include <hip/hip_runtime.h>
#include <hip/hip_bf16.h>

typedef _Float16 f16x8 __attribute__((ext_vector_type(8)));
typedef _Float16 f16x4 __attribute__((ext_vector_type(4)));
typedef float    f32x4 __attribute__((ext_vector_type(4)));

#define B_   64
#define N_   512
#define D_   1024
#define HROWS (B_ * N_)          // 32768
#define EPS_ 1e-5f

__device__ __forceinline__ void gload_lds16(const _Float16* g, _Float16* l) {
    __builtin_amdgcn_global_load_lds(
        (const __attribute__((address_space(1))) void*)g,
        (__attribute__((address_space(3))) void*)l, 16, 0, 0);
}

// ---------------- elementwise / prep kernels ----------------

__global__ void k_cvt_f16(const float* __restrict__ in, _Float16* __restrict__ out, int n4) {
    int i = blockIdx.x * blockDim.x + threadIdx.x;
    int stride = gridDim.x * blockDim.x;
    const float4* in4 = (const float4*)in;
    for (; i < n4; i += stride) {
        float4 v = in4[i];
        f16x4 o;
        o[0] = (_Float16)v.x; o[1] = (_Float16)v.y;
        o[2] = (_Float16)v.z; o[3] = (_Float16)v.w;
        *(f16x4*)(out + (size_t)i * 4) = o;
    }
}

// W [1024][1024] fp32 -> Wt [1024][1024] f16 (transposed)
__global__ void k_transpose_w(const float* __restrict__ in, _Float16* __restrict__ out) {
    __shared__ float tile[32][33];
    int bx = blockIdx.x * 32;   // col base of in == row base of out
    int by = blockIdx.y * 32;   // row base of in
    int tx = threadIdx.x, ty = threadIdx.y;
    #pragma unroll
    for (int r = 0; r < 32; r += 8)
        tile[ty + r][tx] = in[(size_t)(by + ty + r) * 1024 + bx + tx];
    __syncthreads();
    #pragma unroll
    for (int r = 0; r < 32; r += 8)
        out[(size_t)(bx + ty + r) * 1024 + by + tx] = (_Float16)tile[tx][ty + r];
}

// ---------------- BN stats / normalize ----------------

__global__ void k_bnstats(const float* __restrict__ t, const float* __restrict__ gamma,
                          const float* __restrict__ beta, float* __restrict__ scale,
                          float* __restrict__ shift) {
    const int n = blockIdx.x, tid = threadIdx.x;
    float s = 0.f, s2 = 0.f;
    const float* base = t + (size_t)n * 1024 + tid * 4;
    for (int b = 0; b < 64; ++b) {
        float4 v = *(const float4*)(base + (size_t)b * 512 * 1024);
        s  += v.x + v.y + v.z + v.w;
        s2 += v.x * v.x + v.y * v.y + v.z * v.z + v.w * v.w;
    }
    #pragma unroll
    for (int o = 32; o > 0; o >>= 1) { s += __shfl_down(s, o); s2 += __shfl_down(s2, o); }
    __shared__ float rs_[4], rs2_[4];
    int lane = tid & 63, w = tid >> 6;
    if (lane == 0) { rs_[w] = s; rs2_[w] = s2; }
    __syncthreads();
    if (tid == 0) {
        float S  = rs_[0] + rs_[1] + rs_[2] + rs_[3];
        float S2 = rs2_[0] + rs2_[1] + rs2_[2] + rs2_[3];
        float mean = S * (1.f / 65536.f);
        float var  = S2 * (1.f / 65536.f) - mean * mean;
        float r = rsqrtf(var + EPS_);
        float sc = gamma[n] * r;
        scale[n] = sc;
        shift[n] = beta[n] - mean * sc;
    }
}

// per (b,n) row: normalize + leaky, row-mean, write theta f16 and theta_c f16
__global__ void k_bnorm(const float* __restrict__ t, const float* __restrict__ scale,
                        const float* __restrict__ shift, _Float16* __restrict__ theta,
                        _Float16* __restrict__ thetac) {
    const int row = blockIdx.x, tid = threadIdx.x;
    const int n = row & 511;
    const float sc = scale[n], sh = shift[n];
    float4 v = *(const float4*)(t + (size_t)row * 1024 + tid * 4);
    float a0 = fmaf(v.x, sc, sh); a0 = a0 >= 0.f ? a0 : 0.01f * a0;
    float a1 = fmaf(v.y, sc, sh); a1 = a1 >= 0.f ? a1 : 0.01f * a1;
    float a2 = fmaf(v.z, sc, sh); a2 = a2 >= 0.f ? a2 : 0.01f * a2;
    float a3 = fmaf(v.w, sc, sh); a3 = a3 >= 0.f ? a3 : 0.01f * a3;
    float s = a0 + a1 + a2 + a3;
    #pragma unroll
    for (int o = 32; o > 0; o >>= 1) s += __shfl_down(s, o);
    __shared__ float red[4];
    int lane = tid & 63, w = tid >> 6;
    if (lane == 0) red[w] = s;
    __syncthreads();
    const float mean = (red[0] + red[1] + red[2] + red[3]) * (1.f / 1024.f);
    f16x4 th, tc;
    th[0] = (_Float16)a0; th[1] = (_Float16)a1; th[2] = (_Float16)a2; th[3] = (_Float16)a3;
    tc[0] = (_Float16)(a0 - mean); tc[1] = (_Float16)(a1 - mean);
    tc[2] = (_Float16)(a2 - mean); tc[3] = (_Float16)(a3 - mean);
    *(f16x4*)(theta  + (size_t)row * 1024 + tid * 4) = th;
    *(f16x4*)(thetac + (size_t)row * 1024 + tid * 4) = tc;
}

// ---------------- global softmax (per batch, over 512*512) ----------------

__device__ __forceinline__ unsigned f2key(float f) {
    unsigned u = __float_as_uint(f);
    return (u & 0x80000000u) ? ~u : (u | 0x80000000u);
}
__device__ __forceinline__ float key2f(unsigned k) {
    unsigned u = (k & 0x80000000u) ? (k & 0x7fffffffu) : ~k;
    return __uint_as_float(u);
}

__global__ void k_smax_init(unsigned* __restrict__ mkey, float* __restrict__ ssum) {
    int i = threadIdx.x;
    if (i < 64) { mkey[i] = 0u; ssum[i] = 0.f; }
}

__global__ void k_smax_max(const float* __restrict__ sigma, unsigned* __restrict__ mkey) {
    const int b = blockIdx.y, tid = threadIdx.x;
    float4 v = *(const float4*)(sigma + (size_t)b * 262144 + blockIdx.x * 1024 + tid * 4);
    float m = fmaxf(fmaxf(v.x, v.y), fmaxf(v.z, v.w));
    #pragma unroll
    for (int o = 32; o > 0; o >>= 1) m = fmaxf(m, __shfl_down(m, o));
    __shared__ float red[4];
    int lane = tid & 63, w = tid >> 6;
    if (lane == 0) red[w] = m;
    __syncthreads();
    if (tid == 0)
        atomicMax(mkey + b, f2key(fmaxf(fmaxf(red[0], red[1]), fmaxf(red[2], red[3]))));
}

__global__ void k_smax_sum(const float* __restrict__ sigma, const unsigned* __restrict__ mkey,
                           float* __restrict__ ssum) {
    const int b = blockIdx.y, tid = threadIdx.x;
    const float mx = key2f(mkey[b]);
    float4 v = *(const float4*)(sigma + (size_t)b * 262144 + blockIdx.x * 1024 + tid * 4);
    float s = __expf(v.x - mx) + __expf(v.y - mx) + __expf(v.z - mx) + __expf(v.w - mx);
    #pragma unroll
    for (int o = 32; o > 0; o >>= 1) s += __shfl_down(s, o);
    __shared__ float red[4];
    int lane = tid & 63, w = tid >> 6;
    if (lane == 0) red[w] = s;
    __syncthreads();
    if (tid == 0) atomicAdd(ssum + b, red[0] + red[1] + red[2] + red[3]);
}

__global__ void k_smax_write(const float* __restrict__ sigma, const unsigned* __restrict__ mkey,
                             _Float16* __restrict__ att) {
    const int b = blockIdx.y, tid = threadIdx.x;
    const float mx = key2f(mkey[b]);
    size_t ofs = (size_t)b * 262144 + blockIdx.x * 1024 + tid * 4;
    float4 v = *(const float4*)(sigma + ofs);
    f16x4 o;
    o[0] = (_Float16)__expf(v.x - mx); o[1] = (_Float16)__expf(v.y - mx);
    o[2] = (_Float16)__expf(v.z - mx); o[3] = (_Float16)__expf(v.w - mx);
    *(f16x4*)(att + ofs) = o;
}

// ---------------- shared NT GEMM: C = A * B^T (+epilogue per MODE) ----------------
// MODE 0: t   = xb @ W1t^T + b1          fp32 out, M=32768 N=1024 K=1024
// MODE 1: sig = theta_c @ theta^T / 32768 fp32 out, per batch M=N=512 K=1024
// MODE 2: g_t[b][h][m] = (xb @ W2t^T + b2)^T  f16 out, M=32768 N=1024 K=1024
// MODE 3: ag  = att @ g_t^T * (1/ssum[b])     f16 out, per batch M=512 N=1024 K=512
// MODE 4: out = ag@W3 + xb@W4 + b3 + b4       fp32 out, M=32768 N=1024 K=2048 (concat)
//
// Staging: global_load_lds width=16, LDS linear dest. Tile is row-major
// [128 rows][4 chunks of 8 f16], with the chunk index XOR-swizzled per row:
//   physical chunk(r, kg) = r*4 + (kg ^ ((r>>1)&3))
// Write side: 4 consecutive lanes cover one 64B row segment (perm'd 16B pieces)
//   -> wave reads 16 contiguous 64B segments (coalesced).
// Read side: 16-lane fragment read spreads rows over 8 bank-sets, 2-way = free.

template <int MODE>
__global__ __launch_bounds__(256) void k_gemm(
    const _Float16* __restrict__ A0, const _Float16* __restrict__ A1,
    const _Float16* __restrict__ B0, const _Float16* __restrict__ B1,
    const float* __restrict__ bias0, const float* __restrict__ bias1,
    const float* __restrict__ sumptr, void* __restrict__ outp) {

    constexpr int BK = 32;
    __shared__ _Float16 Al[4096];   // 512 chunks of 8 f16
    __shared__ _Float16 Bl[4096];

    const int tid = threadIdx.x, lane = tid & 63, w = tid >> 6;
    const int wm = w >> 1, wn = w & 1;

    int bm, bn, bz = 0;
    if constexpr (MODE == 0 || MODE == 2 || MODE == 4) {
        // XCD-aware swizzle: nwg = 2048, divisible by 8 -> bijective
        const int nwg = gridDim.x;
        const int bid = blockIdx.x;
        const int swz = (bid & 7) * (nwg >> 3) + (bid >> 3);
        bm = swz >> 3;      // 256 M-blocks, contiguous within an XCD
        bn = swz & 7;       // 8 N-blocks
    } else {
        bm = blockIdx.x; bn = blockIdx.y; bz = blockIdx.z;
    }

    int K_, LDA, LDB;
    size_t aOff, bOff;
    if constexpr (MODE == 0 || MODE == 2 || MODE == 4) {
        K_ = (MODE == 4) ? 2048 : 1024; LDA = 1024; LDB = 1024;
        aOff = (size_t)bm * 128 * 1024;
        bOff = (size_t)bn * 128 * 1024;
    } else if constexpr (MODE == 1) {
        K_ = 1024; LDA = 1024; LDB = 1024;
        aOff = ((size_t)bz * 512 + bm * 128) * 1024;
        bOff = ((size_t)bz * 512 + bn * 128) * 1024;
    } else { // MODE 3
        K_ = 512; LDA = 512; LDB = 512;
        aOff = (size_t)bz * 262144 + (size_t)bm * 128 * 512;
        bOff = (size_t)bz * 524288 + (size_t)bn * 128 * 512;
    }

    float oscale = 1.f;
    if constexpr (MODE == 3) oscale = 1.f / sumptr[bz];

    // staging: thread tid fills physical chunks tid and tid+256
    //   chunk L: row = L>>2, k-group to fetch = (L&3) ^ ((L>>3)&3)
    //   (for L+256: same k-group, row+64)
    const int srow = tid >> 2;
    const int skofs = ((tid & 3) ^ ((tid >> 3) & 3)) * 8;
    _Float16* lA0 = &Al[(w * 64) * 8];          // wave-uniform bases
    _Float16* lA1 = &Al[(256 + w * 64) * 8];
    _Float16* lB0 = &Bl[(w * 64) * 8];
    _Float16* lB1 = &Bl[(256 + w * 64) * 8];

    const int lr = lane & 15, kg = lane >> 4;
    const int kswz = kg ^ ((lr >> 1) & 3);      // read-side chunk swizzle

    f32x4 acc[4][4] = {};

    for (int k0 = 0; k0 < K_; k0 += BK) {
        const _Float16* As; const _Float16* Bs; int kk = k0;
        if constexpr (MODE == 4) {
            if (k0 < 1024) { As = A0; Bs = B0; }
            else           { As = A1; Bs = B1; kk = k0 - 1024; }
        } else { As = A0; Bs = B0; }

        gload_lds16(As + aOff + (size_t)srow * LDA + kk + skofs, lA0);
        gload_lds16(As + aOff + (size_t)(srow + 64) * LDA + kk + skofs, lA1);
        gload_lds16(Bs + bOff + (size_t)srow * LDB + kk + skofs, lB0);
        gload_lds16(Bs + bOff + (size_t)(srow + 64) * LDB + kk + skofs, lB1);
        __syncthreads();   // compiler drains vmcnt before barrier

        f16x8 af[4], bf[4];
        #pragma unroll
        for (int m = 0; m < 4; m++)
            af[m] = *(const f16x8*)&Al[((wm * 64 + m * 16 + lr) * 4 + kswz) * 8];
        #pragma unroll
        for (int n = 0; n < 4; n++)
            bf[n] = *(const f16x8*)&Bl[((wn * 64 + n * 16 + lr) * 4 + kswz) * 8];
        #pragma unroll
        for (int m = 0; m < 4; m++)
            #pragma unroll
            for (int n = 0; n < 4; n++)
                acc[m][n] = __builtin_amdgcn_mfma_f32_16x16x32_f16(af[m], bf[n], acc[m][n], 0, 0, 0);
        __syncthreads();
    }

    // epilogue
    #pragma unroll
    for (int m = 0; m < 4; m++) {
        #pragma unroll
        for (int n = 0; n < 4; n++) {
            const int r0 = wm * 64 + m * 16 + kg * 4;
            const int c  = wn * 64 + n * 16 + lr;
            if constexpr (MODE == 0) {
                float* o = (float*)outp;
                const size_t gr0 = (size_t)bm * 128 + r0;
                const int gc = bn * 128 + c;
                const float bias = bias0[gc];
                #pragma unroll
                for (int i = 0; i < 4; i++) o[(gr0 + i) * 1024 + gc] = acc[m][n][i] + bias;
            } else if constexpr (MODE == 1) {
                float* o = (float*)outp + (size_t)bz * 262144;
                const int gr0 = bm * 128 + r0, gc = bn * 128 + c;
                #pragma unroll
                for (int i = 0; i < 4; i++)
                    o[(size_t)(gr0 + i) * 512 + gc] = acc[m][n][i] * (1.f / 32768.f);
            } else if constexpr (MODE == 2) {
                _Float16* o = (_Float16*)outp;
                const int gr0 = bm * 128 + r0;
                const int gc = bn * 128 + c;
                const int bb = gr0 >> 9, mm = gr0 & 511;
                const float bias = bias0[gc];
                f16x4 pk;
                #pragma unroll
                for (int i = 0; i < 4; i++) pk[i] = (_Float16)(acc[m][n][i] + bias);
                *(f16x4*)(o + ((size_t)bb * 1024 + gc) * 512 + mm) = pk;
            } else if constexpr (MODE == 3) {
                _Float16* o = (_Float16*)outp + (size_t)bz * 524288;
                const int gr0 = bm * 128 + r0, gc = bn * 128 + c;
                #pragma unroll
                for (int i = 0; i < 4; i++)
                    o[(size_t)(gr0 + i) * 1024 + gc] = (_Float16)(acc[m][n][i] * oscale);
            } else { // MODE 4
                float* o = (float*)outp;
                const size_t gr0 = (size_t)bm * 128 + r0;
                const int gc = bn * 128 + c;
                const float bias = bias0[gc] + bias1[gc];
                #pragma unroll
                for (int i = 0; i < 4; i++) o[(gr0 + i) * 1024 + gc] = acc[m][n][i] + bias;
            }
        }
    }
}

// ---------------- launcher ----------------

extern "C" void kernel_launch(void* const* d_in, const int* in_sizes, int n_in,
                              void* d_out, int out_size, void* d_ws, size_t ws_size,
                              hipStream_t stream) {
    (void)in_sizes; (void)n_in; (void)out_size; (void)ws_size;
    const float* x     = (const float*)d_in[0];
    const float* W1    = (const float*)d_in[1];
    const float* b1    = (const float*)d_in[2];
    const float* gamma = (const float*)d_in[3];
    const float* beta  = (const float*)d_in[4];
    const float* W2    = (const float*)d_in[5];
    const float* b2    = (const float*)d_in[6];
    const float* W3    = (const float*)d_in[7];
    const float* b3    = (const float*)d_in[8];
    const float* W4    = (const float*)d_in[9];
    const float* b4    = (const float*)d_in[10];

    char* wsb = (char*)d_ws;
    const size_t MB = 1024 * 1024;
    _Float16* xb   = (_Float16*)(wsb);                    // 64 MB
    _Float16* W1t  = (_Float16*)(wsb + 64 * MB);          // 2 MB
    _Float16* W2t  = (_Float16*)(wsb + 66 * MB);
    _Float16* W3t  = (_Float16*)(wsb + 68 * MB);
    _Float16* W4t  = (_Float16*)(wsb + 70 * MB);
    float*    t    = (float*)(wsb + 72 * MB);             // 128 MB
    float*    sigma= (float*)(wsb + 72 * MB);             // alias: t dead after bnorm
    _Float16* att  = (_Float16*)(wsb + 136 * MB);         // alias: inside t region (32 MB)
    _Float16* theta  = (_Float16*)(wsb + 200 * MB);       // 64 MB
    _Float16* thetac = (_Float16*)(wsb + 264 * MB);       // 64 MB
    _Float16* g_t  = theta;                               // alias: theta dead after sigma gemm
    _Float16* ag   = thetac;                              // alias: theta_c dead after sigma gemm
    float*    scl  = (float*)(wsb + 328 * MB);
    float*    shf  = (float*)(wsb + 328 * MB + 4096);
    unsigned* mkey = (unsigned*)(wsb + 328 * MB + 8192);
    float*    ssum = (float*)(wsb + 328 * MB + 8192 + 256);

    // 1. x -> f16
    k_cvt_f16<<<8192, 256, 0, stream>>>(x, xb, (64 * 512 * 1024 * 4) / 4 / 4);
    // 2. transpose weights -> f16 [out][in]
    dim3 tb(32, 8), tg(32, 32);
    k_transpose_w<<<tg, tb, 0, stream>>>(W1, W1t);
    k_transpose_w<<<tg, tb, 0, stream>>>(W2, W2t);
    k_transpose_w<<<tg, tb, 0, stream>>>(W3, W3t);
    k_transpose_w<<<tg, tb, 0, stream>>>(W4, W4t);
    // 3. t = xb @ W1 + b1 (fp32)
    k_gemm<0><<<2048, 256, 0, stream>>>(xb, nullptr, W1t, nullptr, b1, nullptr, nullptr, t);
    // 4. BN stats
    k_bnstats<<<512, 256, 0, stream>>>(t, gamma, beta, scl, shf);
    // 5. normalize + leaky + row-center -> theta, theta_c
    k_bnorm<<<32768, 256, 0, stream>>>(t, scl, shf, theta, thetac);
    // 6. sigma = theta_c @ theta^T / 32768 (per batch)
    k_gemm<1><<<dim3(4, 4, 64), 256, 0, stream>>>(thetac, nullptr, theta, nullptr, nullptr, nullptr, nullptr, sigma);
    // 7-10. global softmax per batch
    k_smax_init<<<1, 64, 0, stream>>>(mkey, ssum);
    k_smax_max<<<dim3(256, 64), 256, 0, stream>>>(sigma, mkey);
    k_smax_sum<<<dim3(256, 64), 256, 0, stream>>>(sigma, mkey, ssum);
    k_smax_write<<<dim3(256, 64), 256, 0, stream>>>(sigma, mkey, att);
    // 11. g_t[b][h][m] = (xb @ W2 + b2)^T
    k_gemm<2><<<2048, 256, 0, stream>>>(xb, nullptr, W2t, nullptr, b2, nullptr, nullptr, g_t);
    // 12. ag = (att @ g) / ssum (per batch)
    k_gemm<3><<<dim3(4, 8, 64), 256, 0, stream>>>(att, nullptr, g_t, nullptr, nullptr, nullptr, ssum, ag);
    // 13. out = ag @ W3 + xb @ W4 + b3 + b4
    k_gemm<4><<<2048, 256, 0, stream>>>(ag, xb, W3t, W4t, b3, b4, nullptr, d_out);
}

// Round 4
// 842.656 us; speedup vs baseline: 1.3416x; 1.0835x over previous
//
#include <hip/hip_runtime.h>
#include <hip/hip_bf16.h>

typedef _Float16 f16x8 __attribute__((ext_vector_type(8)));
typedef _Float16 f16x4 __attribute__((ext_vector_type(4)));
typedef float    f32x4 __attribute__((ext_vector_type(4)));

#define EPS_ 1e-5f

__device__ __forceinline__ void gload_lds16(const _Float16* g, _Float16* l) {
    __builtin_amdgcn_global_load_lds(
        (const __attribute__((address_space(1))) void*)g,
        (__attribute__((address_space(3))) void*)l, 16, 0, 0);
}

// ---------------- elementwise / prep kernels ----------------

__global__ void k_cvt_f16(const float* __restrict__ in, _Float16* __restrict__ out, int n4) {
    int i = blockIdx.x * blockDim.x + threadIdx.x;
    int stride = gridDim.x * blockDim.x;
    const float4* in4 = (const float4*)in;
    for (; i < n4; i += stride) {
        float4 v = in4[i];
        f16x4 o;
        o[0] = (_Float16)v.x; o[1] = (_Float16)v.y;
        o[2] = (_Float16)v.z; o[3] = (_Float16)v.w;
        *(f16x4*)(out + (size_t)i * 4) = o;
    }
}

// W [1024][1024] fp32 -> Wt [1024][1024] f16 (transposed)
__global__ void k_transpose_w(const float* __restrict__ in, _Float16* __restrict__ out) {
    __shared__ float tile[32][33];
    int bx = blockIdx.x * 32;
    int by = blockIdx.y * 32;
    int tx = threadIdx.x, ty = threadIdx.y;
    #pragma unroll
    for (int r = 0; r < 32; r += 8)
        tile[ty + r][tx] = in[(size_t)(by + ty + r) * 1024 + bx + tx];
    __syncthreads();
    #pragma unroll
    for (int r = 0; r < 32; r += 8)
        out[(size_t)(bx + ty + r) * 1024 + by + tx] = (_Float16)tile[tx][ty + r];
}

// b23[o] = sum_h b2[h] * W3[h][o]
__global__ void k_b23(const float* __restrict__ b2, const float* __restrict__ W3,
                      float* __restrict__ b23) {
    const int oo = threadIdx.x & 63, hc = threadIdx.x >> 6;
    const int o = blockIdx.x * 64 + oo;
    float s = 0.f;
    for (int h = hc * 256; h < hc * 256 + 256; ++h) s += b2[h] * W3[(size_t)h * 1024 + o];
    __shared__ float red[4][64];
    red[hc][oo] = s;
    __syncthreads();
    if (threadIdx.x < 64) {
        int o2 = blockIdx.x * 64 + threadIdx.x;
        b23[o2] = red[0][threadIdx.x] + red[1][threadIdx.x] + red[2][threadIdx.x] + red[3][threadIdx.x];
    }
}

// ---------------- BN stats / normalize (t is f16 now) ----------------

__global__ void k_bnstats(const _Float16* __restrict__ t, const float* __restrict__ gamma,
                          const float* __restrict__ beta, float* __restrict__ scale,
                          float* __restrict__ shift) {
    const int n = blockIdx.x, tid = threadIdx.x;
    float s = 0.f, s2 = 0.f;
    const _Float16* base = t + (size_t)n * 1024 + tid * 4;
    for (int b = 0; b < 64; ++b) {
        f16x4 v = *(const f16x4*)(base + (size_t)b * 512 * 1024);
        float x0 = (float)v[0], x1 = (float)v[1], x2 = (float)v[2], x3 = (float)v[3];
        s  += x0 + x1 + x2 + x3;
        s2 += x0 * x0 + x1 * x1 + x2 * x2 + x3 * x3;
    }
    #pragma unroll
    for (int o = 32; o > 0; o >>= 1) { s += __shfl_down(s, o); s2 += __shfl_down(s2, o); }
    __shared__ float rs_[4], rs2_[4];
    int lane = tid & 63, w = tid >> 6;
    if (lane == 0) { rs_[w] = s; rs2_[w] = s2; }
    __syncthreads();
    if (tid == 0) {
        float S  = rs_[0] + rs_[1] + rs_[2] + rs_[3];
        float S2 = rs2_[0] + rs2_[1] + rs2_[2] + rs2_[3];
        float mean = S * (1.f / 65536.f);
        float var  = S2 * (1.f / 65536.f) - mean * mean;
        float r = rsqrtf(var + EPS_);
        float sc = gamma[n] * r;
        scale[n] = sc;
        shift[n] = beta[n] - mean * sc;
    }
}

// normalize + leaky, write theta f16 and row-mean mu
__global__ void k_bnorm(const _Float16* __restrict__ t, const float* __restrict__ scale,
                        const float* __restrict__ shift, _Float16* __restrict__ theta,
                        float* __restrict__ mu) {
    const int row = blockIdx.x, tid = threadIdx.x;
    const int n = row & 511;
    const float sc = scale[n], sh = shift[n];
    f16x4 v = *(const f16x4*)(t + (size_t)row * 1024 + tid * 4);
    float a0 = fmaf((float)v[0], sc, sh); a0 = a0 >= 0.f ? a0 : 0.01f * a0;
    float a1 = fmaf((float)v[1], sc, sh); a1 = a1 >= 0.f ? a1 : 0.01f * a1;
    float a2 = fmaf((float)v[2], sc, sh); a2 = a2 >= 0.f ? a2 : 0.01f * a2;
    float a3 = fmaf((float)v[3], sc, sh); a3 = a3 >= 0.f ? a3 : 0.01f * a3;
    float s = a0 + a1 + a2 + a3;
    #pragma unroll
    for (int o = 32; o > 0; o >>= 1) s += __shfl_down(s, o);
    __shared__ float red[4];
    int lane = tid & 63, w = tid >> 6;
    if (lane == 0) red[w] = s;
    __syncthreads();
    const float mean = (red[0] + red[1] + red[2] + red[3]) * (1.f / 1024.f);
    f16x4 th;
    th[0] = (_Float16)a0; th[1] = (_Float16)a1; th[2] = (_Float16)a2; th[3] = (_Float16)a3;
    *(f16x4*)(theta + (size_t)row * 1024 + tid * 4) = th;
    if (tid == 0) mu[row] = mean;
}

// ---------------- global softmax (per batch, over 512*512) ----------------

__device__ __forceinline__ unsigned f2key(float f) {
    unsigned u = __float_as_uint(f);
    return (u & 0x80000000u) ? ~u : (u | 0x80000000u);
}
__device__ __forceinline__ float key2f(unsigned k) {
    unsigned u = (k & 0x80000000u) ? (k & 0x7fffffffu) : ~k;
    return __uint_as_float(u);
}

__global__ void k_smax_init(unsigned* __restrict__ mkey, float* __restrict__ ssum) {
    int i = threadIdx.x;
    if (i < 64) { mkey[i] = 0u; ssum[i] = 0.f; }
}

__global__ void k_smax_max(const float* __restrict__ sigma, unsigned* __restrict__ mkey) {
    const int b = blockIdx.y, tid = threadIdx.x;
    float4 v = *(const float4*)(sigma + (size_t)b * 262144 + blockIdx.x * 1024 + tid * 4);
    float m = fmaxf(fmaxf(v.x, v.y), fmaxf(v.z, v.w));
    #pragma unroll
    for (int o = 32; o > 0; o >>= 1) m = fmaxf(m, __shfl_down(m, o));
    __shared__ float red[4];
    int lane = tid & 63, w = tid >> 6;
    if (lane == 0) red[w] = m;
    __syncthreads();
    if (tid == 0)
        atomicMax(mkey + b, f2key(fmaxf(fmaxf(red[0], red[1]), fmaxf(red[2], red[3]))));
}

// sum of exp; also per-row sums (block covers exactly rows 2*bx, 2*bx+1)
__global__ void k_smax_sum(const float* __restrict__ sigma, const unsigned* __restrict__ mkey,
                           float* __restrict__ ssum, float* __restrict__ rsum) {
    const int b = blockIdx.y, tid = threadIdx.x;
    const float mx = key2f(mkey[b]);
    float4 v = *(const float4*)(sigma + (size_t)b * 262144 + blockIdx.x * 1024 + tid * 4);
    float s = __expf(v.x - mx) + __expf(v.y - mx) + __expf(v.z - mx) + __expf(v.w - mx);
    #pragma unroll
    for (int o = 32; o > 0; o >>= 1) s += __shfl_down(s, o);
    __shared__ float red[4];
    int lane = tid & 63, w = tid >> 6;
    if (lane == 0) red[w] = s;
    __syncthreads();
    if (tid == 0) {
        atomicAdd(ssum + b, red[0] + red[1] + red[2] + red[3]);
        rsum[b * 512 + blockIdx.x * 2]     = red[0] + red[1];
        rsum[b * 512 + blockIdx.x * 2 + 1] = red[2] + red[3];
    }
}

__global__ void k_smax_write(const float* __restrict__ sigma, const unsigned* __restrict__ mkey,
                             _Float16* __restrict__ att) {
    const int b = blockIdx.y, tid = threadIdx.x;
    const float mx = key2f(mkey[b]);
    size_t ofs = (size_t)b * 262144 + blockIdx.x * 1024 + tid * 4;
    float4 v = *(const float4*)(sigma + ofs);
    f16x4 o;
    o[0] = (_Float16)__expf(v.x - mx); o[1] = (_Float16)__expf(v.y - mx);
    o[2] = (_Float16)__expf(v.z - mx); o[3] = (_Float16)__expf(v.w - mx);
    *(f16x4*)(att + ofs) = o;
}

// ---------------- shared NT GEMM: C = A * B^T, 2-phase prefetch ----------------
// M0: t(f16)   = xb @ W1t^T + b1             M=32768 N=1024 K=1024  [swizzled grid]
// M1: sigma    = theta@theta^T /32768 - mu_i*mu_j/32  fp32, per batch, K=1024
// M2: gwt[b][o][m] = (xb @ W23t^T)^T  f16    M=32768 N=1024 K=1024  [swizzled]
// M3: p(f16)   = att@gwt^T*osc + rsum*osc*b23 + b3    per batch M=512 N=1024 K=512
// M4: out(f32) = xb @ W4t^T + b4 + p         M=32768 N=1024 K=1024  [swizzled]
// M5: W23t     = W3t @ W2h^T  f16 row-major  M=1024 N=1024 K=1024   [xy grid]
//
// LDS: linear dest for global_load_lds, per-row XOR swizzle of 16B chunk idx:
//   physical chunk(r, kg) = r*4 + (kg ^ ((r>>1)&3))  -- write coalesced, read 2-way free.

template <int MODE>
__global__ __launch_bounds__(256) void k_gemm(
    const _Float16* __restrict__ A0, const _Float16* __restrict__ B0,
    const float* __restrict__ biasf, const float* __restrict__ auxA,
    const float* __restrict__ auxB, const _Float16* __restrict__ auxH,
    const float* __restrict__ sumptr, void* __restrict__ outp) {

    constexpr int BK = 32;
    __shared__ _Float16 Al[2][4096];
    __shared__ _Float16 Bl[2][4096];

    const int tid = threadIdx.x, lane = tid & 63, w = tid >> 6;
    const int wm = w >> 1, wn = w & 1;

    int bm, bn, bz = 0;
    if constexpr (MODE == 0 || MODE == 2 || MODE == 4) {
        const int nwg = gridDim.x;
        const int bid = blockIdx.x;
        const int swz = (bid & 7) * (nwg >> 3) + (bid >> 3);
        bm = swz >> 3;
        bn = swz & 7;
    } else {
        bm = blockIdx.x; bn = blockIdx.y; bz = blockIdx.z;
    }

    int K_, LDA, LDB;
    size_t aOff, bOff;
    if constexpr (MODE == 0 || MODE == 2 || MODE == 4) {
        K_ = 1024; LDA = 1024; LDB = 1024;
        aOff = (size_t)bm * 128 * 1024;
        bOff = (size_t)bn * 128 * 1024;
    } else if constexpr (MODE == 1 || MODE == 5) {
        K_ = 1024; LDA = 1024; LDB = 1024;
        aOff = ((size_t)bz * 512 + bm * 128) * 1024;
        bOff = ((size_t)bz * 512 + bn * 128) * 1024;
    } else { // MODE 3
        K_ = 512; LDA = 512; LDB = 512;
        aOff = (size_t)bz * 262144 + (size_t)bm * 128 * 512;
        bOff = (size_t)bz * 524288 + (size_t)bn * 128 * 512;
    }

    float oscale = 1.f;
    if constexpr (MODE == 3) oscale = 1.f / sumptr[bz];

    const int srow = tid >> 2;
    const int skofs = ((tid & 3) ^ ((tid >> 3) & 3)) * 8;

    const int lr = lane & 15, kg = lane >> 4;
    const int kswz = kg ^ ((lr >> 1) & 3);

    f32x4 acc[4][4] = {};

    auto STAGE = [&](int buf, int kk) {
        gload_lds16(A0 + aOff + (size_t)srow * LDA + kk + skofs, &Al[buf][(w * 64) * 8]);
        gload_lds16(A0 + aOff + (size_t)(srow + 64) * LDA + kk + skofs, &Al[buf][(256 + w * 64) * 8]);
        gload_lds16(B0 + bOff + (size_t)srow * LDB + kk + skofs, &Bl[buf][(w * 64) * 8]);
        gload_lds16(B0 + bOff + (size_t)(srow + 64) * LDB + kk + skofs, &Bl[buf][(256 + w * 64) * 8]);
    };

    STAGE(0, 0);
    __syncthreads();
    int cur = 0;

    for (int k0 = 0; k0 < K_; k0 += BK) {
        if (k0 + BK < K_) STAGE(cur ^ 1, k0 + BK);

        f16x8 af[4], bf[4];
        #pragma unroll
        for (int m = 0; m < 4; m++)
            af[m] = *(const f16x8*)&Al[cur][((wm * 64 + m * 16 + lr) * 4 + kswz) * 8];
        #pragma unroll
        for (int n = 0; n < 4; n++)
            bf[n] = *(const f16x8*)&Bl[cur][((wn * 64 + n * 16 + lr) * 4 + kswz) * 8];
        #pragma unroll
        for (int m = 0; m < 4; m++)
            #pragma unroll
            for (int n = 0; n < 4; n++)
                acc[m][n] = __builtin_amdgcn_mfma_f32_16x16x32_f16(af[m], bf[n], acc[m][n], 0, 0, 0);
        __syncthreads();
        cur ^= 1;
    }

    // epilogue
    #pragma unroll
    for (int m = 0; m < 4; m++) {
        #pragma unroll
        for (int n = 0; n < 4; n++) {
            const int r0 = wm * 64 + m * 16 + kg * 4;
            const int c  = wn * 64 + n * 16 + lr;
            if constexpr (MODE == 0) {
                _Float16* o = (_Float16*)outp;
                const size_t gr0 = (size_t)bm * 128 + r0;
                const int gc = bn * 128 + c;
                const float bias = biasf[gc];
                #pragma unroll
                for (int i = 0; i < 4; i++)
                    o[(gr0 + i) * 1024 + gc] = (_Float16)(acc[m][n][i] + bias);
            } else if constexpr (MODE == 1) {
                float* o = (float*)outp + (size_t)bz * 262144;
                const int gr0 = bm * 128 + r0, gc = bn * 128 + c;
                const float mj = auxA[bz * 512 + gc];
                #pragma unroll
                for (int i = 0; i < 4; i++) {
                    const float mi = auxA[bz * 512 + gr0 + i];
                    o[(size_t)(gr0 + i) * 512 + gc] =
                        acc[m][n][i] * (1.f / 32768.f) - mi * mj * (1.f / 32.f);
                }
            } else if constexpr (MODE == 2) {
                _Float16* o = (_Float16*)outp;
                const int gr0 = bm * 128 + r0;
                const int gc = bn * 128 + c;
                const int bb = gr0 >> 9, mm = gr0 & 511;
                f16x4 pk;
                #pragma unroll
                for (int i = 0; i < 4; i++) pk[i] = (_Float16)acc[m][n][i];
                *(f16x4*)(o + ((size_t)bb * 1024 + gc) * 512 + mm) = pk;
            } else if constexpr (MODE == 3) {
                _Float16* o = (_Float16*)outp + (size_t)bz * 524288;
                const int gr0 = bm * 128 + r0, gc = bn * 128 + c;
                const float b23v = auxB[gc], b3v = biasf[gc];
                #pragma unroll
                for (int i = 0; i < 4; i++) {
                    const float rs = auxA[bz * 512 + gr0 + i];
                    o[(size_t)(gr0 + i) * 1024 + gc] =
                        (_Float16)(acc[m][n][i] * oscale + rs * oscale * b23v + b3v);
                }
            } else if constexpr (MODE == 4) {
                float* o = (float*)outp;
                const size_t gr0 = (size_t)bm * 128 + r0;
                const int gc = bn * 128 + c;
                const float bias = biasf[gc];
                #pragma unroll
                for (int i = 0; i < 4; i++)
                    o[(gr0 + i) * 1024 + gc] =
                        acc[m][n][i] + bias + (float)auxH[(gr0 + i) * 1024 + gc];
            } else { // MODE 5: plain f16 row-major, no bias
                _Float16* o = (_Float16*)outp;
                const int gr0 = bm * 128 + r0, gc = bn * 128 + c;
                #pragma unroll
                for (int i = 0; i < 4; i++)
                    o[(size_t)(gr0 + i) * 1024 + gc] = (_Float16)acc[m][n][i];
            }
        }
    }
}

// ---------------- launcher ----------------

extern "C" void kernel_launch(void* const* d_in, const int* in_sizes, int n_in,
                              void* d_out, int out_size, void* d_ws, size_t ws_size,
                              hipStream_t stream) {
    (void)in_sizes; (void)n_in; (void)out_size; (void)ws_size;
    const float* x     = (const float*)d_in[0];
    const float* W1    = (const float*)d_in[1];
    const float* b1    = (const float*)d_in[2];
    const float* gamma = (const float*)d_in[3];
    const float* beta  = (const float*)d_in[4];
    const float* W2    = (const float*)d_in[5];
    const float* b2    = (const float*)d_in[6];
    const float* W3    = (const float*)d_in[7];
    const float* b3    = (const float*)d_in[8];
    const float* W4    = (const float*)d_in[9];
    const float* b4    = (const float*)d_in[10];

    char* wsb = (char*)d_ws;
    const size_t MB = 1024 * 1024;
    _Float16* xb   = (_Float16*)(wsb);                    // 0-64 MB
    _Float16* W1t  = (_Float16*)(wsb + 64 * MB);          // 2 MB each
    _Float16* W3t  = (_Float16*)(wsb + 66 * MB);
    _Float16* W4t  = (_Float16*)(wsb + 68 * MB);
    _Float16* W2h  = (_Float16*)(wsb + 70 * MB);          // W2 f16, NOT transposed
    _Float16* W23t = (_Float16*)(wsb + 72 * MB);          // (W2@W3)^T f16
    float*    b23  = (float*)(wsb + 74 * MB);             // 4 KB
    float*    scl  = (float*)(wsb + 74 * MB + 8192);
    float*    shf  = (float*)(wsb + 74 * MB + 16384);
    unsigned* mkey = (unsigned*)(wsb + 74 * MB + 24576);
    float*    ssum = (float*)(wsb + 74 * MB + 28672);
    float*    mu   = (float*)(wsb + 75 * MB);             // 128 KB
    float*    rsum = (float*)(wsb + 76 * MB);             // 128 KB
    _Float16* t    = (_Float16*)(wsb + 80 * MB);          // 64 MB (f16)
    float*    sigma= (float*)(wsb + 80 * MB);             // alias: t dead after bnorm
    _Float16* att  = (_Float16*)(wsb + 144 * MB);         // 32 MB
    _Float16* theta= (_Float16*)(wsb + 176 * MB);         // 64 MB
    _Float16* p    = (_Float16*)(wsb + 176 * MB);         // alias: theta dead after sigma
    _Float16* gwt  = (_Float16*)(wsb + 240 * MB);         // 64 MB

    // prep
    k_cvt_f16<<<8192, 256, 0, stream>>>(x, xb, 64 * 512 * 1024 / 4);
    k_cvt_f16<<<1024, 256, 0, stream>>>(W2, W2h, 1024 * 1024 / 4);
    dim3 tb(32, 8), tg(32, 32);
    k_transpose_w<<<tg, tb, 0, stream>>>(W1, W1t);
    k_transpose_w<<<tg, tb, 0, stream>>>(W3, W3t);
    k_transpose_w<<<tg, tb, 0, stream>>>(W4, W4t);
    // W23t = W3t @ W2h^T  (stored [o][i] = (W2@W3)^T)
    k_gemm<5><<<dim3(8, 8, 1), 256, 0, stream>>>(W3t, W2h, nullptr, nullptr, nullptr, nullptr, nullptr, W23t);
    k_b23<<<16, 256, 0, stream>>>(b2, W3, b23);
    // t = xb @ W1 + b1 (f16)
    k_gemm<0><<<2048, 256, 0, stream>>>(xb, W1t, b1, nullptr, nullptr, nullptr, nullptr, t);
    // BN stats + normalize
    k_bnstats<<<512, 256, 0, stream>>>(t, gamma, beta, scl, shf);
    k_bnorm<<<32768, 256, 0, stream>>>(t, scl, shf, theta, mu);
    // sigma = theta@theta^T/32768 - mu_i*mu_j/32  (symmetric form)
    k_gemm<1><<<dim3(4, 4, 64), 256, 0, stream>>>(theta, theta, nullptr, mu, nullptr, nullptr, nullptr, sigma);
    // global softmax per batch (+ row sums)
    k_smax_init<<<1, 64, 0, stream>>>(mkey, ssum);
    k_smax_max<<<dim3(256, 64), 256, 0, stream>>>(sigma, mkey);
    k_smax_sum<<<dim3(256, 64), 256, 0, stream>>>(sigma, mkey, ssum, rsum);
    k_smax_write<<<dim3(256, 64), 256, 0, stream>>>(sigma, mkey, att);
    // gwt = (xb @ W23)^T  per batch layout [b][o][m]
    k_gemm<2><<<2048, 256, 0, stream>>>(xb, W23t, nullptr, nullptr, nullptr, nullptr, nullptr, gwt);
    // p = att@gw*osc + rsum*osc*b23 + b3   (f16 [b][n][o])
    k_gemm<3><<<dim3(4, 8, 64), 256, 0, stream>>>(att, gwt, b3, rsum, b23, nullptr, ssum, p);
    // out = xb @ W4 + b4 + p
    k_gemm<4><<<2048, 256, 0, stream>>>(xb, W4t, b4, nullptr, nullptr, p, nullptr, d_out);
}

// Round 5
// 534.566 us; speedup vs baseline: 2.1148x; 1.5763x over previous
//
#include <hip/hip_runtime.h>
#include <hip/hip_bf16.h>

typedef _Float16 f16x8 __attribute__((ext_vector_type(8)));
typedef _Float16 f16x4 __attribute__((ext_vector_type(4)));
typedef float    f32x4 __attribute__((ext_vector_type(4)));

#define EPS_ 1e-5f

__device__ __forceinline__ void gload_lds16(const _Float16* g, _Float16* l) {
    __builtin_amdgcn_global_load_lds(
        (const __attribute__((address_space(1))) void*)g,
        (__attribute__((address_space(3))) void*)l, 16, 0, 0);
}

// ---------------- elementwise / prep kernels ----------------

__global__ void k_cvt_f16(const float* __restrict__ in, _Float16* __restrict__ out, int n4) {
    int i = blockIdx.x * blockDim.x + threadIdx.x;
    int stride = gridDim.x * blockDim.x;
    const float4* in4 = (const float4*)in;
    for (; i < n4; i += stride) {
        float4 v = in4[i];
        f16x4 o;
        o[0] = (_Float16)v.x; o[1] = (_Float16)v.y;
        o[2] = (_Float16)v.z; o[3] = (_Float16)v.w;
        *(f16x4*)(out + (size_t)i * 4) = o;
    }
}

// W [1024][1024] fp32 -> Wt [1024][1024] f16 (transposed)
__global__ void k_transpose_w(const float* __restrict__ in, _Float16* __restrict__ out) {
    __shared__ float tile[32][33];
    int bx = blockIdx.x * 32;
    int by = blockIdx.y * 32;
    int tx = threadIdx.x, ty = threadIdx.y;
    #pragma unroll
    for (int r = 0; r < 32; r += 8)
        tile[ty + r][tx] = in[(size_t)(by + ty + r) * 1024 + bx + tx];
    __syncthreads();
    #pragma unroll
    for (int r = 0; r < 32; r += 8)
        out[(size_t)(bx + ty + r) * 1024 + by + tx] = (_Float16)tile[tx][ty + r];
}

// b23[o] = sum_h b2[h] * W3[h][o]
__global__ void k_b23(const float* __restrict__ b2, const float* __restrict__ W3,
                      float* __restrict__ b23) {
    const int oo = threadIdx.x & 63, hc = threadIdx.x >> 6;
    const int o = blockIdx.x * 64 + oo;
    float s = 0.f;
    for (int h = hc * 256; h < hc * 256 + 256; ++h) s += b2[h] * W3[(size_t)h * 1024 + o];
    __shared__ float red[4][64];
    red[hc][oo] = s;
    __syncthreads();
    if (threadIdx.x < 64) {
        int o2 = blockIdx.x * 64 + threadIdx.x;
        b23[o2] = red[0][threadIdx.x] + red[1][threadIdx.x] + red[2][threadIdx.x] + red[3][threadIdx.x];
    }
}

// ---------------- BN stats / normalize (t in f16) ----------------

__global__ void k_bnstats(const _Float16* __restrict__ t, const float* __restrict__ gamma,
                          const float* __restrict__ beta, float* __restrict__ scale,
                          float* __restrict__ shift) {
    const int n = blockIdx.x, tid = threadIdx.x;
    float s = 0.f, s2 = 0.f;
    const _Float16* base = t + (size_t)n * 1024 + tid * 4;
    for (int b = 0; b < 64; ++b) {
        f16x4 v = *(const f16x4*)(base + (size_t)b * 512 * 1024);
        float x0 = (float)v[0], x1 = (float)v[1], x2 = (float)v[2], x3 = (float)v[3];
        s  += x0 + x1 + x2 + x3;
        s2 += x0 * x0 + x1 * x1 + x2 * x2 + x3 * x3;
    }
    #pragma unroll
    for (int o = 32; o > 0; o >>= 1) { s += __shfl_down(s, o); s2 += __shfl_down(s2, o); }
    __shared__ float rs_[4], rs2_[4];
    int lane = tid & 63, w = tid >> 6;
    if (lane == 0) { rs_[w] = s; rs2_[w] = s2; }
    __syncthreads();
    if (tid == 0) {
        float S  = rs_[0] + rs_[1] + rs_[2] + rs_[3];
        float S2 = rs2_[0] + rs2_[1] + rs2_[2] + rs2_[3];
        float mean = S * (1.f / 65536.f);
        float var  = S2 * (1.f / 65536.f) - mean * mean;
        float r = rsqrtf(var + EPS_);
        float sc = gamma[n] * r;
        scale[n] = sc;
        shift[n] = beta[n] - mean * sc;
    }
}

// normalize + leaky, write theta f16 and row-mean mu
__global__ void k_bnorm(const _Float16* __restrict__ t, const float* __restrict__ scale,
                        const float* __restrict__ shift, _Float16* __restrict__ theta,
                        float* __restrict__ mu) {
    const int row = blockIdx.x, tid = threadIdx.x;
    const int n = row & 511;
    const float sc = scale[n], sh = shift[n];
    f16x4 v = *(const f16x4*)(t + (size_t)row * 1024 + tid * 4);
    float a0 = fmaf((float)v[0], sc, sh); a0 = a0 >= 0.f ? a0 : 0.01f * a0;
    float a1 = fmaf((float)v[1], sc, sh); a1 = a1 >= 0.f ? a1 : 0.01f * a1;
    float a2 = fmaf((float)v[2], sc, sh); a2 = a2 >= 0.f ? a2 : 0.01f * a2;
    float a3 = fmaf((float)v[3], sc, sh); a3 = a3 >= 0.f ? a3 : 0.01f * a3;
    float s = a0 + a1 + a2 + a3;
    #pragma unroll
    for (int o = 32; o > 0; o >>= 1) s += __shfl_down(s, o);
    __shared__ float red[4];
    int lane = tid & 63, w = tid >> 6;
    if (lane == 0) red[w] = s;
    __syncthreads();
    const float mean = (red[0] + red[1] + red[2] + red[3]) * (1.f / 1024.f);
    f16x4 th;
    th[0] = (_Float16)a0; th[1] = (_Float16)a1; th[2] = (_Float16)a2; th[3] = (_Float16)a3;
    *(f16x4*)(theta + (size_t)row * 1024 + tid * 4) = th;
    if (tid == 0) mu[row] = mean;
}

// rsum[b][j] = sum_bn part[bn][b][j]; ssum[b] = sum_j rsum[b][j]
__global__ void k_ssum(const float* __restrict__ part, float* __restrict__ rsum,
                       float* __restrict__ ssum) {
    const int b = blockIdx.x, j = threadIdx.x;   // 512 threads
    const int idx = b * 512 + j;
    float s = part[idx] + part[32768 + idx] + part[65536 + idx] + part[98304 + idx];
    rsum[idx] = s;
    #pragma unroll
    for (int o = 32; o > 0; o >>= 1) s += __shfl_down(s, o);
    __shared__ float red[8];
    if ((j & 63) == 0) red[j >> 6] = s;
    __syncthreads();
    if (j == 0) {
        float tt = 0.f;
        #pragma unroll
        for (int k = 0; k < 8; k++) tt += red[k];
        ssum[b] = tt;
    }
}

// ---------------- shared NT GEMM: C = A * B^T (+epilogue per MODE) ----------------
// M0: t(f16) = xb @ W1t^T + b1                  M=32768 N=1024 K=1024 [swizzled]
// M1: att(f16) = exp(theta@theta^T/32768 - mu_i*mu_j/32), per batch; row-partials
// M2: gwt[b][o][m] = (xb @ W23t^T)^T  f16       M=32768 N=1024 K=1024 [swizzled]
// M3: out(f32) = (att@gwt^T)*osc + xb@W4t^T + rsum*osc*b23 + b3 + b4   per batch
// M5: W23t = W3t @ W2h^T  f16 row-major
//
// Staging: global_load_lds w16, linear LDS, per-row XOR swizzle of 16B chunk:
//   physical chunk(r, kg) = r*4 + (kg ^ ((r>>1)&3))  (write coalesced, read 2-way free)

template <int MODE>
__global__ __launch_bounds__(256) void k_gemm(
    const _Float16* __restrict__ A0, const _Float16* __restrict__ B0,
    const _Float16* __restrict__ A1, const _Float16* __restrict__ B1,
    const float* __restrict__ biasf, const float* __restrict__ biasg,
    const float* __restrict__ auxA, float* __restrict__ auxW,
    const float* __restrict__ sumptr, void* __restrict__ outp) {

    constexpr int BK = 32;
    __shared__ _Float16 Al[4096];
    __shared__ _Float16 Bl[4096];

    const int tid = threadIdx.x, lane = tid & 63, w = tid >> 6;
    const int wm = w >> 1, wn = w & 1;

    int bm, bn, bz = 0;
    if constexpr (MODE == 0 || MODE == 2) {
        const int nwg = gridDim.x;
        const int bid = blockIdx.x;
        const int swz = (bid & 7) * (nwg >> 3) + (bid >> 3);
        bm = swz >> 3;
        bn = swz & 7;
    } else {
        bm = blockIdx.x; bn = blockIdx.y; bz = blockIdx.z;
    }

    const int srow = tid >> 2;
    const int skofs = ((tid & 3) ^ ((tid >> 3) & 3)) * 8;
    _Float16* lA0 = &Al[(w * 64) * 8];
    _Float16* lA1 = &Al[(256 + w * 64) * 8];
    _Float16* lB0 = &Bl[(w * 64) * 8];
    _Float16* lB1 = &Bl[(256 + w * 64) * 8];

    const int lr = lane & 15, kg = lane >> 4;
    const int kswz = kg ^ ((lr >> 1) & 3);

    f32x4 acc[4][4] = {};

    auto KLOOP = [&](const _Float16* As, const _Float16* Bs, size_t aO, size_t bO,
                     int LDa, int LDb, int Ksz) {
        for (int k0 = 0; k0 < Ksz; k0 += BK) {
            gload_lds16(As + aO + (size_t)srow * LDa + k0 + skofs, lA0);
            gload_lds16(As + aO + (size_t)(srow + 64) * LDa + k0 + skofs, lA1);
            gload_lds16(Bs + bO + (size_t)srow * LDb + k0 + skofs, lB0);
            gload_lds16(Bs + bO + (size_t)(srow + 64) * LDb + k0 + skofs, lB1);
            __syncthreads();
            f16x8 af[4], bf[4];
            #pragma unroll
            for (int m = 0; m < 4; m++)
                af[m] = *(const f16x8*)&Al[((wm * 64 + m * 16 + lr) * 4 + kswz) * 8];
            #pragma unroll
            for (int n = 0; n < 4; n++)
                bf[n] = *(const f16x8*)&Bl[((wn * 64 + n * 16 + lr) * 4 + kswz) * 8];
            #pragma unroll
            for (int m = 0; m < 4; m++)
                #pragma unroll
                for (int n = 0; n < 4; n++)
                    acc[m][n] = __builtin_amdgcn_mfma_f32_16x16x32_f16(af[m], bf[n], acc[m][n], 0, 0, 0);
            __syncthreads();
        }
    };

    float oscale = 1.f;
    if constexpr (MODE == 0 || MODE == 2) {
        KLOOP(A0, B0, (size_t)bm * 128 * 1024, (size_t)bn * 128 * 1024, 1024, 1024, 1024);
    } else if constexpr (MODE == 1 || MODE == 5) {
        KLOOP(A0, B0, ((size_t)bz * 512 + bm * 128) * 1024,
                      ((size_t)bz * 512 + bn * 128) * 1024, 1024, 1024, 1024);
    } else { // MODE 3: [att|xb] @ [gwt|W4t]^T with mid-loop rescale
        KLOOP(A0, B0, (size_t)bz * 262144 + (size_t)bm * 128 * 512,
                      (size_t)bz * 524288 + (size_t)bn * 128 * 512, 512, 512, 512);
        oscale = 1.f / sumptr[bz];
        #pragma unroll
        for (int m = 0; m < 4; m++)
            #pragma unroll
            for (int n = 0; n < 4; n++)
                #pragma unroll
                for (int i = 0; i < 4; i++) acc[m][n][i] *= oscale;
        KLOOP(A1, B1, ((size_t)bz * 512 + bm * 128) * 1024,
                      (size_t)bn * 128 * 1024, 1024, 1024, 1024);
    }

    // ---------------- epilogues ----------------
    if constexpr (MODE == 1) {
        __shared__ float rbuf[2][128];
        _Float16* o = (_Float16*)outp + (size_t)bz * 262144;
        #pragma unroll
        for (int m = 0; m < 4; m++) {
            const int r0 = wm * 64 + m * 16 + kg * 4;
            float rs[4] = {0.f, 0.f, 0.f, 0.f};
            #pragma unroll
            for (int n = 0; n < 4; n++) {
                const int gc = bn * 128 + wn * 64 + n * 16 + lr;
                const float mj = auxA[bz * 512 + gc];
                #pragma unroll
                for (int i = 0; i < 4; i++) {
                    const float mi = auxA[bz * 512 + bm * 128 + r0 + i];
                    const float e = __expf(acc[m][n][i] * (1.f / 32768.f) - mi * mj * (1.f / 32.f));
                    o[(size_t)(bm * 128 + r0 + i) * 512 + gc] = (_Float16)e;
                    rs[i] += e;
                }
            }
            #pragma unroll
            for (int i = 0; i < 4; i++) {
                float v = rs[i];
                v += __shfl_xor(v, 1); v += __shfl_xor(v, 2);
                v += __shfl_xor(v, 4); v += __shfl_xor(v, 8);
                if (lr == 0) rbuf[wn][r0 + i] = v;
            }
        }
        __syncthreads();
        if (tid < 128)
            auxW[(size_t)bn * 32768 + bz * 512 + bm * 128 + tid] = rbuf[0][tid] + rbuf[1][tid];
        return;
    }

    #pragma unroll
    for (int m = 0; m < 4; m++) {
        #pragma unroll
        for (int n = 0; n < 4; n++) {
            const int r0 = wm * 64 + m * 16 + kg * 4;
            const int c  = wn * 64 + n * 16 + lr;
            if constexpr (MODE == 0) {
                _Float16* o = (_Float16*)outp;
                const size_t gr0 = (size_t)bm * 128 + r0;
                const int gc = bn * 128 + c;
                const float bias = biasf[gc];
                #pragma unroll
                for (int i = 0; i < 4; i++)
                    o[(gr0 + i) * 1024 + gc] = (_Float16)(acc[m][n][i] + bias);
            } else if constexpr (MODE == 2) {
                _Float16* o = (_Float16*)outp;
                const int gr0 = bm * 128 + r0;
                const int gc = bn * 128 + c;
                const int bb = gr0 >> 9, mm = gr0 & 511;
                f16x4 pk;
                #pragma unroll
                for (int i = 0; i < 4; i++) pk[i] = (_Float16)acc[m][n][i];
                *(f16x4*)(o + ((size_t)bb * 1024 + gc) * 512 + mm) = pk;
            } else if constexpr (MODE == 3) {
                float* o = (float*)outp;
                const int gc = bn * 128 + c;
                const float tail = biasf[gc] + biasg[gc];
                const float b23v = auxW[gc];
                #pragma unroll
                for (int i = 0; i < 4; i++) {
                    const int lrow = bm * 128 + r0 + i;
                    const size_t grow = (size_t)bz * 512 + lrow;
                    o[grow * 1024 + gc] =
                        acc[m][n][i] + auxA[bz * 512 + lrow] * oscale * b23v + tail;
                }
            } else { // MODE 5
                _Float16* o = (_Float16*)outp;
                const int gr0 = bm * 128 + r0, gc = bn * 128 + c;
                #pragma unroll
                for (int i = 0; i < 4; i++)
                    o[(size_t)(gr0 + i) * 1024 + gc] = (_Float16)acc[m][n][i];
            }
        }
    }
}

// ---------------- launcher ----------------

extern "C" void kernel_launch(void* const* d_in, const int* in_sizes, int n_in,
                              void* d_out, int out_size, void* d_ws, size_t ws_size,
                              hipStream_t stream) {
    (void)in_sizes; (void)n_in; (void)out_size; (void)ws_size;
    const float* x     = (const float*)d_in[0];
    const float* W1    = (const float*)d_in[1];
    const float* b1    = (const float*)d_in[2];
    const float* gamma = (const float*)d_in[3];
    const float* beta  = (const float*)d_in[4];
    const float* W2    = (const float*)d_in[5];
    const float* b2    = (const float*)d_in[6];
    const float* W3    = (const float*)d_in[7];
    const float* b3    = (const float*)d_in[8];
    const float* W4    = (const float*)d_in[9];
    const float* b4    = (const float*)d_in[10];

    char* wsb = (char*)d_ws;
    const size_t MB = 1024 * 1024;
    _Float16* xb    = (_Float16*)(wsb);                   // 64 MB
    _Float16* W1t   = (_Float16*)(wsb + 64 * MB);
    _Float16* W3t   = (_Float16*)(wsb + 66 * MB);
    _Float16* W4t   = (_Float16*)(wsb + 68 * MB);
    _Float16* W2h   = (_Float16*)(wsb + 70 * MB);
    _Float16* W23t  = (_Float16*)(wsb + 72 * MB);
    float*    b23   = (float*)(wsb + 74 * MB);            // 4 KB
    float*    scl   = (float*)(wsb + 74 * MB + 8192);
    float*    shf   = (float*)(wsb + 74 * MB + 16384);
    float*    ssum  = (float*)(wsb + 74 * MB + 24576);
    float*    mu    = (float*)(wsb + 75 * MB);            // 128 KB
    float*    rsum  = (float*)(wsb + 76 * MB);            // 128 KB
    float*    rpart = (float*)(wsb + 77 * MB);            // 512 KB
    _Float16* t     = (_Float16*)(wsb + 80 * MB);         // 64 MB
    _Float16* theta = (_Float16*)(wsb + 144 * MB);        // 64 MB
    _Float16* att   = (_Float16*)(wsb + 208 * MB);        // 32 MB
    _Float16* gwt   = (_Float16*)(wsb + 240 * MB);        // 64 MB

    // prep
    k_cvt_f16<<<8192, 256, 0, stream>>>(x, xb, 64 * 512 * 1024 / 4);
    k_cvt_f16<<<1024, 256, 0, stream>>>(W2, W2h, 1024 * 1024 / 4);
    dim3 tb(32, 8), tg(32, 32);
    k_transpose_w<<<tg, tb, 0, stream>>>(W1, W1t);
    k_transpose_w<<<tg, tb, 0, stream>>>(W3, W3t);
    k_transpose_w<<<tg, tb, 0, stream>>>(W4, W4t);
    // W23t = (W2@W3)^T
    k_gemm<5><<<dim3(8, 8, 1), 256, 0, stream>>>(W3t, W2h, nullptr, nullptr,
        nullptr, nullptr, nullptr, nullptr, nullptr, W23t);
    k_b23<<<16, 256, 0, stream>>>(b2, W3, b23);
    // t = xb @ W1 + b1 (f16)
    k_gemm<0><<<2048, 256, 0, stream>>>(xb, W1t, nullptr, nullptr,
        b1, nullptr, nullptr, nullptr, nullptr, t);
    // BN stats + normalize
    k_bnstats<<<512, 256, 0, stream>>>(t, gamma, beta, scl, shf);
    k_bnorm<<<32768, 256, 0, stream>>>(t, scl, shf, theta, mu);
    // att = exp(sigma) + per-block row partials (no global max needed: |sigma| << 1)
    k_gemm<1><<<dim3(4, 4, 64), 256, 0, stream>>>(theta, theta, nullptr, nullptr,
        nullptr, nullptr, mu, rpart, nullptr, att);
    // rsum / ssum
    k_ssum<<<64, 512, 0, stream>>>(rpart, rsum, ssum);
    // gwt = (xb @ W23)^T per batch [b][o][m]
    k_gemm<2><<<2048, 256, 0, stream>>>(xb, W23t, nullptr, nullptr,
        nullptr, nullptr, nullptr, nullptr, nullptr, gwt);
    // out = att@gwt*osc + xb@W4 + rsum*osc*b23 + b3 + b4
    k_gemm<3><<<dim3(4, 8, 64), 256, 0, stream>>>(att, gwt, xb, W4t,
        b3, b4, rsum, b23, ssum, d_out);
}

// Round 6
// 530.030 us; speedup vs baseline: 2.1329x; 1.0086x over previous
//
#include <hip/hip_runtime.h>
#include <hip/hip_bf16.h>

typedef _Float16 f16x8 __attribute__((ext_vector_type(8)));
typedef _Float16 f16x4 __attribute__((ext_vector_type(4)));
typedef float    f32x4 __attribute__((ext_vector_type(4)));

#define EPS_ 1e-5f

__device__ __forceinline__ void gload_lds16(const _Float16* g, _Float16* l) {
    __builtin_amdgcn_global_load_lds(
        (const __attribute__((address_space(1))) void*)g,
        (__attribute__((address_space(3))) void*)l, 16, 0, 0);
}

// ---------------- elementwise / prep kernels ----------------

__global__ void k_cvt_f16(const float* __restrict__ in, _Float16* __restrict__ out, int n4) {
    int i = blockIdx.x * blockDim.x + threadIdx.x;
    int stride = gridDim.x * blockDim.x;
    const float4* in4 = (const float4*)in;
    for (; i < n4; i += stride) {
        float4 v = in4[i];
        f16x4 o;
        o[0] = (_Float16)v.x; o[1] = (_Float16)v.y;
        o[2] = (_Float16)v.z; o[3] = (_Float16)v.w;
        *(f16x4*)(out + (size_t)i * 4) = o;
    }
}

// W [1024][1024] fp32 -> Wt [1024][1024] f16 (transposed)
__global__ void k_transpose_w(const float* __restrict__ in, _Float16* __restrict__ out) {
    __shared__ float tile[32][33];
    int bx = blockIdx.x * 32;
    int by = blockIdx.y * 32;
    int tx = threadIdx.x, ty = threadIdx.y;
    #pragma unroll
    for (int r = 0; r < 32; r += 8)
        tile[ty + r][tx] = in[(size_t)(by + ty + r) * 1024 + bx + tx];
    __syncthreads();
    #pragma unroll
    for (int r = 0; r < 32; r += 8)
        out[(size_t)(bx + ty + r) * 1024 + by + tx] = (_Float16)tile[tx][ty + r];
}

// b23[o] = sum_h b2[h] * W3[h][o]
__global__ void k_b23(const float* __restrict__ b2, const float* __restrict__ W3,
                      float* __restrict__ b23) {
    const int oo = threadIdx.x & 63, hc = threadIdx.x >> 6;
    const int o = blockIdx.x * 64 + oo;
    float s = 0.f;
    for (int h = hc * 256; h < hc * 256 + 256; ++h) s += b2[h] * W3[(size_t)h * 1024 + o];
    __shared__ float red[4][64];
    red[hc][oo] = s;
    __syncthreads();
    if (threadIdx.x < 64) {
        int o2 = blockIdx.x * 64 + threadIdx.x;
        b23[o2] = red[0][threadIdx.x] + red[1][threadIdx.x] + red[2][threadIdx.x] + red[3][threadIdx.x];
    }
}

// ---------------- BN stats / normalize (t in f16) ----------------

__global__ void k_bnstats(const _Float16* __restrict__ t, const float* __restrict__ gamma,
                          const float* __restrict__ beta, float* __restrict__ scale,
                          float* __restrict__ shift) {
    const int n = blockIdx.x, tid = threadIdx.x;
    float s = 0.f, s2 = 0.f;
    const _Float16* base = t + (size_t)n * 1024 + tid * 4;
    for (int b = 0; b < 64; ++b) {
        f16x4 v = *(const f16x4*)(base + (size_t)b * 512 * 1024);
        float x0 = (float)v[0], x1 = (float)v[1], x2 = (float)v[2], x3 = (float)v[3];
        s  += x0 + x1 + x2 + x3;
        s2 += x0 * x0 + x1 * x1 + x2 * x2 + x3 * x3;
    }
    #pragma unroll
    for (int o = 32; o > 0; o >>= 1) { s += __shfl_down(s, o); s2 += __shfl_down(s2, o); }
    __shared__ float rs_[4], rs2_[4];
    int lane = tid & 63, w = tid >> 6;
    if (lane == 0) { rs_[w] = s; rs2_[w] = s2; }
    __syncthreads();
    if (tid == 0) {
        float S  = rs_[0] + rs_[1] + rs_[2] + rs_[3];
        float S2 = rs2_[0] + rs2_[1] + rs2_[2] + rs2_[3];
        float mean = S * (1.f / 65536.f);
        float var  = S2 * (1.f / 65536.f) - mean * mean;
        float r = rsqrtf(var + EPS_);
        float sc = gamma[n] * r;
        scale[n] = sc;
        shift[n] = beta[n] - mean * sc;
    }
}

// normalize + leaky, write theta f16 and row-mean mu
__global__ void k_bnorm(const _Float16* __restrict__ t, const float* __restrict__ scale,
                        const float* __restrict__ shift, _Float16* __restrict__ theta,
                        float* __restrict__ mu) {
    const int row = blockIdx.x, tid = threadIdx.x;
    const int n = row & 511;
    const float sc = scale[n], sh = shift[n];
    f16x4 v = *(const f16x4*)(t + (size_t)row * 1024 + tid * 4);
    float a0 = fmaf((float)v[0], sc, sh); a0 = a0 >= 0.f ? a0 : 0.01f * a0;
    float a1 = fmaf((float)v[1], sc, sh); a1 = a1 >= 0.f ? a1 : 0.01f * a1;
    float a2 = fmaf((float)v[2], sc, sh); a2 = a2 >= 0.f ? a2 : 0.01f * a2;
    float a3 = fmaf((float)v[3], sc, sh); a3 = a3 >= 0.f ? a3 : 0.01f * a3;
    float s = a0 + a1 + a2 + a3;
    #pragma unroll
    for (int o = 32; o > 0; o >>= 1) s += __shfl_down(s, o);
    __shared__ float red[4];
    int lane = tid & 63, w = tid >> 6;
    if (lane == 0) red[w] = s;
    __syncthreads();
    const float mean = (red[0] + red[1] + red[2] + red[3]) * (1.f / 1024.f);
    f16x4 th;
    th[0] = (_Float16)a0; th[1] = (_Float16)a1; th[2] = (_Float16)a2; th[3] = (_Float16)a3;
    *(f16x4*)(theta + (size_t)row * 1024 + tid * 4) = th;
    if (tid == 0) mu[row] = mean;
}

// rsum[b][j] = sum_bn part[bn][b][j]; ssum[b] = sum_j rsum[b][j]
__global__ void k_ssum(const float* __restrict__ part, float* __restrict__ rsum,
                       float* __restrict__ ssum) {
    const int b = blockIdx.x, j = threadIdx.x;   // 512 threads
    const int idx = b * 512 + j;
    float s = part[idx] + part[32768 + idx] + part[65536 + idx] + part[98304 + idx];
    rsum[idx] = s;
    #pragma unroll
    for (int o = 32; o > 0; o >>= 1) s += __shfl_down(s, o);
    __shared__ float red[8];
    if ((j & 63) == 0) red[j >> 6] = s;
    __syncthreads();
    if (j == 0) {
        float tt = 0.f;
        #pragma unroll
        for (int k = 0; k < 8; k++) tt += red[k];
        ssum[b] = tt;
    }
}

// ---------------- old 128^2 GEMM (kept for MODE 1 [sigma+exp] and MODE 5) ----------------

template <int MODE>
__global__ __launch_bounds__(256) void k_gemm(
    const _Float16* __restrict__ A0, const _Float16* __restrict__ B0,
    const float* __restrict__ auxA, float* __restrict__ auxW,
    void* __restrict__ outp) {

    constexpr int BK = 32;
    __shared__ _Float16 Al[4096];
    __shared__ _Float16 Bl[4096];

    const int tid = threadIdx.x, lane = tid & 63, w = tid >> 6;
    const int wm = w >> 1, wn = w & 1;
    const int bm = blockIdx.x, bn = blockIdx.y, bz = blockIdx.z;

    const int srow = tid >> 2;
    const int skofs = ((tid & 3) ^ ((tid >> 3) & 3)) * 8;
    _Float16* lA0 = &Al[(w * 64) * 8];
    _Float16* lA1 = &Al[(256 + w * 64) * 8];
    _Float16* lB0 = &Bl[(w * 64) * 8];
    _Float16* lB1 = &Bl[(256 + w * 64) * 8];

    const int lr = lane & 15, kg = lane >> 4;
    const int kswz = kg ^ ((lr >> 1) & 3);

    f32x4 acc[4][4] = {};

    const size_t aO = ((size_t)bz * 512 + bm * 128) * 1024;
    const size_t bO = ((size_t)bz * 512 + bn * 128) * 1024;
    for (int k0 = 0; k0 < 1024; k0 += BK) {
        gload_lds16(A0 + aO + (size_t)srow * 1024 + k0 + skofs, lA0);
        gload_lds16(A0 + aO + (size_t)(srow + 64) * 1024 + k0 + skofs, lA1);
        gload_lds16(B0 + bO + (size_t)srow * 1024 + k0 + skofs, lB0);
        gload_lds16(B0 + bO + (size_t)(srow + 64) * 1024 + k0 + skofs, lB1);
        __syncthreads();
        f16x8 af[4], bf[4];
        #pragma unroll
        for (int m = 0; m < 4; m++)
            af[m] = *(const f16x8*)&Al[((wm * 64 + m * 16 + lr) * 4 + kswz) * 8];
        #pragma unroll
        for (int n = 0; n < 4; n++)
            bf[n] = *(const f16x8*)&Bl[((wn * 64 + n * 16 + lr) * 4 + kswz) * 8];
        #pragma unroll
        for (int m = 0; m < 4; m++)
            #pragma unroll
            for (int n = 0; n < 4; n++)
                acc[m][n] = __builtin_amdgcn_mfma_f32_16x16x32_f16(af[m], bf[n], acc[m][n], 0, 0, 0);
        __syncthreads();
    }

    if constexpr (MODE == 1) {
        __shared__ float rbuf[2][128];
        _Float16* o = (_Float16*)outp + (size_t)bz * 262144;
        #pragma unroll
        for (int m = 0; m < 4; m++) {
            const int r0 = wm * 64 + m * 16 + kg * 4;
            float rs[4] = {0.f, 0.f, 0.f, 0.f};
            #pragma unroll
            for (int n = 0; n < 4; n++) {
                const int gc = bn * 128 + wn * 64 + n * 16 + lr;
                const float mj = auxA[bz * 512 + gc];
                #pragma unroll
                for (int i = 0; i < 4; i++) {
                    const float mi = auxA[bz * 512 + bm * 128 + r0 + i];
                    const float e = __expf(acc[m][n][i] * (1.f / 32768.f) - mi * mj * (1.f / 32.f));
                    o[(size_t)(bm * 128 + r0 + i) * 512 + gc] = (_Float16)e;
                    rs[i] += e;
                }
            }
            #pragma unroll
            for (int i = 0; i < 4; i++) {
                float v = rs[i];
                v += __shfl_xor(v, 1); v += __shfl_xor(v, 2);
                v += __shfl_xor(v, 4); v += __shfl_xor(v, 8);
                if (lr == 0) rbuf[wn][r0 + i] = v;
            }
        }
        __syncthreads();
        if (tid < 128)
            auxW[(size_t)bn * 32768 + bz * 512 + bm * 128 + tid] = rbuf[0][tid] + rbuf[1][tid];
    } else { // MODE 5: plain f16 row-major
        _Float16* o = (_Float16*)outp;
        #pragma unroll
        for (int m = 0; m < 4; m++) {
            #pragma unroll
            for (int n = 0; n < 4; n++) {
                const int r0 = wm * 64 + m * 16 + kg * 4;
                const int gc = bn * 128 + wn * 64 + n * 16 + lr;
                #pragma unroll
                for (int i = 0; i < 4; i++)
                    o[(size_t)(bm * 128 + r0 + i) * 1024 + gc] = (_Float16)acc[m][n][i];
            }
        }
    }
}

// ---------------- 256^2 ring-pipelined GEMM (counted vmcnt, 4-slot LDS ring) ----------------
// M0: t(f16) = xb @ W1t^T + b1                M=32768 N=1024 K=1024
// M2: gwt[b][o][m] = (xb @ W23t^T)^T  f16     M=32768 N=1024 K=1024
// M3: out(f32) = (att@gwt^T)*osc + xb@W4t^T + rsum*osc*b23 + b3 + b4   (K = 512 | 1024)
//
// 512 thr = 8 waves (2x4), per-wave out 128x64, BK=32, ring of 4 K-step slots.
// Phase t: vmcnt(8) [stage t landed, t+1/t+2 in flight] -> barrier -> STAGE(t+3)
//          [writes slot (t-1)&3, readers passed barrier] -> ds_read + 32 MFMA.

template <int MODE>
__global__ __launch_bounds__(512) void k_gemm2(
    const _Float16* __restrict__ A0, const _Float16* __restrict__ B0,
    const _Float16* __restrict__ A1, const _Float16* __restrict__ B1,
    const float* __restrict__ biasf, const float* __restrict__ biasg,
    const float* __restrict__ auxA, const float* __restrict__ auxB,
    const float* __restrict__ sumptr, void* __restrict__ outp) {

    __shared__ _Float16 LA[4][8192];
    __shared__ _Float16 LB[4][8192];

    const int tid = threadIdx.x, lane = tid & 63, wid = tid >> 6;
    const int wm = wid >> 2, wn = wid & 3;
    const int lr = lane & 15, kq = lane >> 4;

    // XCD swizzle: grid 512 (%8==0), contiguous chunk of 64 per XCD
    const int swz = (blockIdx.x & 7) * 64 + (blockIdx.x >> 3);
    int bm, bn, bz = 0;
    if constexpr (MODE == 3) { bz = swz >> 3; bm = (swz >> 2) & 1; bn = swz & 3; }
    else { bm = swz >> 2; bn = swz & 3; }

    constexpr int NTA = 16;                       // MODE3 segment-A phases
    constexpr int NT = (MODE == 3) ? 48 : 32;

    float oscale = 1.f;
    if constexpr (MODE == 3) oscale = 1.f / sumptr[bz];

    // staging geometry: instruction j in {0,1} covers chunk (j*512 + tid)
    const int r0 = tid >> 2,          kg0 = (tid & 3) ^ ((r0 >> 1) & 3);
    const int r1 = (512 + tid) >> 2,  kg1 = (tid & 3) ^ ((r1 >> 1) & 3);
    const int ldsb0 = (wid * 64) * 8;             // wave-uniform LDS dest bases
    const int ldsb1 = (512 + wid * 64) * 8;

    auto STAGE = [&](int s) {
        const _Float16 *Ap, *Bp; int lda, ldb, kk; size_t aoff, boff;
        if constexpr (MODE == 3) {
            if (s < NTA) {
                Ap = A0; lda = 512;  aoff = (size_t)bz * 262144 + (size_t)bm * 256 * 512;
                Bp = B0; ldb = 512;  boff = (size_t)bz * 524288 + (size_t)bn * 256 * 512;
                kk = s * 32;
            } else {
                Ap = A1; lda = 1024; aoff = ((size_t)bz * 512 + bm * 256) * 1024;
                Bp = B1; ldb = 1024; boff = (size_t)bn * 256 * 1024;
                kk = (s - NTA) * 32;
            }
        } else {
            Ap = A0; lda = 1024; aoff = (size_t)bm * 256 * 1024;
            Bp = B0; ldb = 1024; boff = (size_t)bn * 256 * 1024;
            kk = s * 32;
        }
        _Float16* la = LA[s & 3];
        _Float16* lb = LB[s & 3];
        gload_lds16(Ap + aoff + (size_t)r0 * lda + kk + kg0 * 8, la + ldsb0);
        gload_lds16(Ap + aoff + (size_t)r1 * lda + kk + kg1 * 8, la + ldsb1);
        gload_lds16(Bp + boff + (size_t)r0 * ldb + kk + kg0 * 8, lb + ldsb0);
        gload_lds16(Bp + boff + (size_t)r1 * ldb + kk + kg1 * 8, lb + ldsb1);
    };

    f32x4 acc[8][4] = {};

    STAGE(0); STAGE(1); STAGE(2);
    for (int t = 0; t < NT; ++t) {
        if (t + 2 < NT)      asm volatile("s_waitcnt vmcnt(8)" ::: "memory");
        else if (t + 1 < NT) asm volatile("s_waitcnt vmcnt(4)" ::: "memory");
        else                 asm volatile("s_waitcnt vmcnt(0)" ::: "memory");
        __builtin_amdgcn_s_barrier();
        if (t + 3 < NT) STAGE(t + 3);
        if constexpr (MODE == 3) {
            if (t == NTA) {
                #pragma unroll
                for (int m = 0; m < 8; m++)
                    #pragma unroll
                    for (int n = 0; n < 4; n++)
                        #pragma unroll
                        for (int i = 0; i < 4; i++) acc[m][n][i] *= oscale;
            }
        }
        const _Float16* la = LA[t & 3];
        const _Float16* lb = LB[t & 3];
        f16x8 bfr[4];
        #pragma unroll
        for (int n = 0; n < 4; n++) {
            const int r = wn * 64 + n * 16 + lr;
            bfr[n] = *(const f16x8*)&lb[(r * 4 + (kq ^ ((r >> 1) & 3))) * 8];
        }
        #pragma unroll
        for (int m = 0; m < 8; m++) {
            const int r = wm * 128 + m * 16 + lr;
            f16x8 af = *(const f16x8*)&la[(r * 4 + (kq ^ ((r >> 1) & 3))) * 8];
            #pragma unroll
            for (int n = 0; n < 4; n++)
                acc[m][n] = __builtin_amdgcn_mfma_f32_16x16x32_f16(af, bfr[n], acc[m][n], 0, 0, 0);
        }
    }

    // ---------------- epilogues ----------------
    #pragma unroll
    for (int m = 0; m < 8; m++) {
        #pragma unroll
        for (int n = 0; n < 4; n++) {
            const int gc = bn * 256 + wn * 64 + n * 16 + lr;
            const int gr0 = bm * 256 + wm * 128 + m * 16 + kq * 4;
            if constexpr (MODE == 0) {
                _Float16* o = (_Float16*)outp;
                const float bias = biasf[gc];
                #pragma unroll
                for (int i = 0; i < 4; i++)
                    o[(size_t)(gr0 + i) * 1024 + gc] = (_Float16)(acc[m][n][i] + bias);
            } else if constexpr (MODE == 2) {
                _Float16* o = (_Float16*)outp;
                const int bb = gr0 >> 9, mm = gr0 & 511;
                f16x4 pk;
                #pragma unroll
                for (int i = 0; i < 4; i++) pk[i] = (_Float16)acc[m][n][i];
                *(f16x4*)(o + ((size_t)bb * 1024 + gc) * 512 + mm) = pk;
            } else { // MODE 3
                float* o = (float*)outp;
                const float tail = biasf[gc] + biasg[gc];
                const float b23v = auxB[gc];
                #pragma unroll
                for (int i = 0; i < 4; i++) {
                    const int row = gr0 + i;   // 0..511
                    o[((size_t)bz * 512 + row) * 1024 + gc] =
                        acc[m][n][i] + auxA[bz * 512 + row] * oscale * b23v + tail;
                }
            }
        }
    }
}

// ---------------- launcher ----------------

extern "C" void kernel_launch(void* const* d_in, const int* in_sizes, int n_in,
                              void* d_out, int out_size, void* d_ws, size_t ws_size,
                              hipStream_t stream) {
    (void)in_sizes; (void)n_in; (void)out_size; (void)ws_size;
    const float* x     = (const float*)d_in[0];
    const float* W1    = (const float*)d_in[1];
    const float* b1    = (const float*)d_in[2];
    const float* gamma = (const float*)d_in[3];
    const float* beta  = (const float*)d_in[4];
    const float* W2    = (const float*)d_in[5];
    const float* b2    = (const float*)d_in[6];
    const float* W3    = (const float*)d_in[7];
    const float* b3    = (const float*)d_in[8];
    const float* W4    = (const float*)d_in[9];
    const float* b4    = (const float*)d_in[10];

    char* wsb = (char*)d_ws;
    const size_t MB = 1024 * 1024;
    _Float16* xb    = (_Float16*)(wsb);                   // 64 MB
    _Float16* W1t   = (_Float16*)(wsb + 64 * MB);
    _Float16* W3t   = (_Float16*)(wsb + 66 * MB);
    _Float16* W4t   = (_Float16*)(wsb + 68 * MB);
    _Float16* W2h   = (_Float16*)(wsb + 70 * MB);
    _Float16* W23t  = (_Float16*)(wsb + 72 * MB);
    float*    b23   = (float*)(wsb + 74 * MB);            // 4 KB
    float*    scl   = (float*)(wsb + 74 * MB + 8192);
    float*    shf   = (float*)(wsb + 74 * MB + 16384);
    float*    ssum  = (float*)(wsb + 74 * MB + 24576);
    float*    mu    = (float*)(wsb + 75 * MB);            // 128 KB
    float*    rsum  = (float*)(wsb + 76 * MB);            // 128 KB
    float*    rpart = (float*)(wsb + 77 * MB);            // 512 KB
    _Float16* t     = (_Float16*)(wsb + 80 * MB);         // 64 MB
    _Float16* theta = (_Float16*)(wsb + 144 * MB);        // 64 MB
    _Float16* att   = (_Float16*)(wsb + 208 * MB);        // 32 MB
    _Float16* gwt   = (_Float16*)(wsb + 240 * MB);        // 64 MB

    // prep
    k_cvt_f16<<<8192, 256, 0, stream>>>(x, xb, 64 * 512 * 1024 / 4);
    k_cvt_f16<<<1024, 256, 0, stream>>>(W2, W2h, 1024 * 1024 / 4);
    dim3 tb(32, 8), tg(32, 32);
    k_transpose_w<<<tg, tb, 0, stream>>>(W1, W1t);
    k_transpose_w<<<tg, tb, 0, stream>>>(W3, W3t);
    k_transpose_w<<<tg, tb, 0, stream>>>(W4, W4t);
    // W23t = (W2@W3)^T
    k_gemm<5><<<dim3(8, 8, 1), 256, 0, stream>>>(W3t, W2h, nullptr, nullptr, W23t);
    k_b23<<<16, 256, 0, stream>>>(b2, W3, b23);
    // t = xb @ W1 + b1 (f16)  [ring-pipelined]
    k_gemm2<0><<<512, 512, 0, stream>>>(xb, W1t, nullptr, nullptr,
        b1, nullptr, nullptr, nullptr, nullptr, t);
    // BN stats + normalize
    k_bnstats<<<512, 256, 0, stream>>>(t, gamma, beta, scl, shf);
    k_bnorm<<<32768, 256, 0, stream>>>(t, scl, shf, theta, mu);
    // att = exp(sigma) + per-block row partials
    k_gemm<1><<<dim3(4, 4, 64), 256, 0, stream>>>(theta, theta, mu, rpart, att);
    // rsum / ssum
    k_ssum<<<64, 512, 0, stream>>>(rpart, rsum, ssum);
    // gwt = (xb @ W23)^T per batch [b][o][m]  [ring-pipelined]
    k_gemm2<2><<<512, 512, 0, stream>>>(xb, W23t, nullptr, nullptr,
        nullptr, nullptr, nullptr, nullptr, nullptr, gwt);
    // out = att@gwt*osc + xb@W4 + rsum*osc*b23 + b3 + b4  [ring-pipelined]
    k_gemm2<3><<<512, 512, 0, stream>>>(att, gwt, xb, W4t,
        b3, b4, rsum, b23, ssum, d_out);
}

// Round 7
// 503.271 us; speedup vs baseline: 2.2463x; 1.0532x over previous
//
#include <hip/hip_runtime.h>
#include <hip/hip_bf16.h>

typedef _Float16 f16x8 __attribute__((ext_vector_type(8)));
typedef _Float16 f16x4 __attribute__((ext_vector_type(4)));
typedef float    f32x4 __attribute__((ext_vector_type(4)));

#define EPS_ 1e-5f

__device__ __forceinline__ void gload_lds16(const _Float16* g, _Float16* l) {
    __builtin_amdgcn_global_load_lds(
        (const __attribute__((address_space(1))) void*)g,
        (__attribute__((address_space(3))) void*)l, 16, 0, 0);
}

// ---------------- elementwise / prep kernels ----------------

__global__ void k_cvt_f16(const float* __restrict__ in, _Float16* __restrict__ out, int n4) {
    int i = blockIdx.x * blockDim.x + threadIdx.x;
    int stride = gridDim.x * blockDim.x;
    const float4* in4 = (const float4*)in;
    for (; i < n4; i += stride) {
        float4 v = in4[i];
        f16x4 o;
        o[0] = (_Float16)v.x; o[1] = (_Float16)v.y;
        o[2] = (_Float16)v.z; o[3] = (_Float16)v.w;
        *(f16x4*)(out + (size_t)i * 4) = o;
    }
}

// W [1024][1024] fp32 -> Wt [1024][1024] f16 (transposed)
__global__ void k_transpose_w(const float* __restrict__ in, _Float16* __restrict__ out) {
    __shared__ float tile[32][33];
    int bx = blockIdx.x * 32;
    int by = blockIdx.y * 32;
    int tx = threadIdx.x, ty = threadIdx.y;
    #pragma unroll
    for (int r = 0; r < 32; r += 8)
        tile[ty + r][tx] = in[(size_t)(by + ty + r) * 1024 + bx + tx];
    __syncthreads();
    #pragma unroll
    for (int r = 0; r < 32; r += 8)
        out[(size_t)(bx + ty + r) * 1024 + by + tx] = (_Float16)tile[tx][ty + r];
}

// b23[o] = sum_h b2[h] * W3[h][o]
__global__ void k_b23(const float* __restrict__ b2, const float* __restrict__ W3,
                      float* __restrict__ b23) {
    const int oo = threadIdx.x & 63, hc = threadIdx.x >> 6;
    const int o = blockIdx.x * 64 + oo;
    float s = 0.f;
    for (int h = hc * 256; h < hc * 256 + 256; ++h) s += b2[h] * W3[(size_t)h * 1024 + o];
    __shared__ float red[4][64];
    red[hc][oo] = s;
    __syncthreads();
    if (threadIdx.x < 64) {
        int o2 = blockIdx.x * 64 + threadIdx.x;
        b23[o2] = red[0][threadIdx.x] + red[1][threadIdx.x] + red[2][threadIdx.x] + red[3][threadIdx.x];
    }
}

// ---------------- BN stats / normalize (t in f16) ----------------

__global__ void k_bnstats(const _Float16* __restrict__ t, const float* __restrict__ gamma,
                          const float* __restrict__ beta, float* __restrict__ scale,
                          float* __restrict__ shift) {
    const int n = blockIdx.x, tid = threadIdx.x;
    float s = 0.f, s2 = 0.f;
    const _Float16* base = t + (size_t)n * 1024 + tid * 4;
    for (int b = 0; b < 64; ++b) {
        f16x4 v = *(const f16x4*)(base + (size_t)b * 512 * 1024);
        float x0 = (float)v[0], x1 = (float)v[1], x2 = (float)v[2], x3 = (float)v[3];
        s  += x0 + x1 + x2 + x3;
        s2 += x0 * x0 + x1 * x1 + x2 * x2 + x3 * x3;
    }
    #pragma unroll
    for (int o = 32; o > 0; o >>= 1) { s += __shfl_down(s, o); s2 += __shfl_down(s2, o); }
    __shared__ float rs_[4], rs2_[4];
    int lane = tid & 63, w = tid >> 6;
    if (lane == 0) { rs_[w] = s; rs2_[w] = s2; }
    __syncthreads();
    if (tid == 0) {
        float S  = rs_[0] + rs_[1] + rs_[2] + rs_[3];
        float S2 = rs2_[0] + rs2_[1] + rs2_[2] + rs2_[3];
        float mean = S * (1.f / 65536.f);
        float var  = S2 * (1.f / 65536.f) - mean * mean;
        float r = rsqrtf(var + EPS_);
        float sc = gamma[n] * r;
        scale[n] = sc;
        shift[n] = beta[n] - mean * sc;
    }
}

// normalize + leaky, write theta f16 and row-mean mu
__global__ void k_bnorm(const _Float16* __restrict__ t, const float* __restrict__ scale,
                        const float* __restrict__ shift, _Float16* __restrict__ theta,
                        float* __restrict__ mu) {
    const int row = blockIdx.x, tid = threadIdx.x;
    const int n = row & 511;
    const float sc = scale[n], sh = shift[n];
    f16x4 v = *(const f16x4*)(t + (size_t)row * 1024 + tid * 4);
    float a0 = fmaf((float)v[0], sc, sh); a0 = a0 >= 0.f ? a0 : 0.01f * a0;
    float a1 = fmaf((float)v[1], sc, sh); a1 = a1 >= 0.f ? a1 : 0.01f * a1;
    float a2 = fmaf((float)v[2], sc, sh); a2 = a2 >= 0.f ? a2 : 0.01f * a2;
    float a3 = fmaf((float)v[3], sc, sh); a3 = a3 >= 0.f ? a3 : 0.01f * a3;
    float s = a0 + a1 + a2 + a3;
    #pragma unroll
    for (int o = 32; o > 0; o >>= 1) s += __shfl_down(s, o);
    __shared__ float red[4];
    int lane = tid & 63, w = tid >> 6;
    if (lane == 0) red[w] = s;
    __syncthreads();
    const float mean = (red[0] + red[1] + red[2] + red[3]) * (1.f / 1024.f);
    f16x4 th;
    th[0] = (_Float16)a0; th[1] = (_Float16)a1; th[2] = (_Float16)a2; th[3] = (_Float16)a3;
    *(f16x4*)(theta + (size_t)row * 1024 + tid * 4) = th;
    if (tid == 0) mu[row] = mean;
}

// rsum[b][j] = sum_bn part[bn][b][j]; ssum[b] = sum_j rsum[b][j]
__global__ void k_ssum(const float* __restrict__ part, float* __restrict__ rsum,
                       float* __restrict__ ssum) {
    const int b = blockIdx.x, j = threadIdx.x;   // 512 threads
    const int idx = b * 512 + j;
    float s = part[idx] + part[32768 + idx] + part[65536 + idx] + part[98304 + idx];
    rsum[idx] = s;
    #pragma unroll
    for (int o = 32; o > 0; o >>= 1) s += __shfl_down(s, o);
    __shared__ float red[8];
    if ((j & 63) == 0) red[j >> 6] = s;
    __syncthreads();
    if (j == 0) {
        float tt = 0.f;
        #pragma unroll
        for (int k = 0; k < 8; k++) tt += red[k];
        ssum[b] = tt;
    }
}

// ---------------- old 128^2 GEMM (kept for MODE 1 [sigma+exp] and MODE 5) ----------------

template <int MODE>
__global__ __launch_bounds__(256) void k_gemm(
    const _Float16* __restrict__ A0, const _Float16* __restrict__ B0,
    const float* __restrict__ auxA, float* __restrict__ auxW,
    void* __restrict__ outp) {

    constexpr int BK = 32;
    __shared__ _Float16 Al[4096];
    __shared__ _Float16 Bl[4096];

    const int tid = threadIdx.x, lane = tid & 63, w = tid >> 6;
    const int wm = w >> 1, wn = w & 1;
    const int bm = blockIdx.x, bn = blockIdx.y, bz = blockIdx.z;

    const int srow = tid >> 2;
    const int skofs = ((tid & 3) ^ ((tid >> 3) & 3)) * 8;
    _Float16* lA0 = &Al[(w * 64) * 8];
    _Float16* lA1 = &Al[(256 + w * 64) * 8];
    _Float16* lB0 = &Bl[(w * 64) * 8];
    _Float16* lB1 = &Bl[(256 + w * 64) * 8];

    const int lr = lane & 15, kg = lane >> 4;
    const int kswz = kg ^ ((lr >> 1) & 3);

    f32x4 acc[4][4] = {};

    const size_t aO = ((size_t)bz * 512 + bm * 128) * 1024;
    const size_t bO = ((size_t)bz * 512 + bn * 128) * 1024;
    for (int k0 = 0; k0 < 1024; k0 += BK) {
        gload_lds16(A0 + aO + (size_t)srow * 1024 + k0 + skofs, lA0);
        gload_lds16(A0 + aO + (size_t)(srow + 64) * 1024 + k0 + skofs, lA1);
        gload_lds16(B0 + bO + (size_t)srow * 1024 + k0 + skofs, lB0);
        gload_lds16(B0 + bO + (size_t)(srow + 64) * 1024 + k0 + skofs, lB1);
        __syncthreads();
        f16x8 af[4], bf[4];
        #pragma unroll
        for (int m = 0; m < 4; m++)
            af[m] = *(const f16x8*)&Al[((wm * 64 + m * 16 + lr) * 4 + kswz) * 8];
        #pragma unroll
        for (int n = 0; n < 4; n++)
            bf[n] = *(const f16x8*)&Bl[((wn * 64 + n * 16 + lr) * 4 + kswz) * 8];
        #pragma unroll
        for (int m = 0; m < 4; m++)
            #pragma unroll
            for (int n = 0; n < 4; n++)
                acc[m][n] = __builtin_amdgcn_mfma_f32_16x16x32_f16(af[m], bf[n], acc[m][n], 0, 0, 0);
        __syncthreads();
    }

    if constexpr (MODE == 1) {
        __shared__ float rbuf[2][128];
        _Float16* o = (_Float16*)outp + (size_t)bz * 262144;
        #pragma unroll
        for (int m = 0; m < 4; m++) {
            const int r0 = wm * 64 + m * 16 + kg * 4;
            float rs[4] = {0.f, 0.f, 0.f, 0.f};
            #pragma unroll
            for (int n = 0; n < 4; n++) {
                const int gc = bn * 128 + wn * 64 + n * 16 + lr;
                const float mj = auxA[bz * 512 + gc];
                #pragma unroll
                for (int i = 0; i < 4; i++) {
                    const float mi = auxA[bz * 512 + bm * 128 + r0 + i];
                    const float e = __expf(acc[m][n][i] * (1.f / 32768.f) - mi * mj * (1.f / 32.f));
                    o[(size_t)(bm * 128 + r0 + i) * 512 + gc] = (_Float16)e;
                    rs[i] += e;
                }
            }
            #pragma unroll
            for (int i = 0; i < 4; i++) {
                float v = rs[i];
                v += __shfl_xor(v, 1); v += __shfl_xor(v, 2);
                v += __shfl_xor(v, 4); v += __shfl_xor(v, 8);
                if (lr == 0) rbuf[wn][r0 + i] = v;
            }
        }
        __syncthreads();
        if (tid < 128)
            auxW[(size_t)bn * 32768 + bz * 512 + bm * 128 + tid] = rbuf[0][tid] + rbuf[1][tid];
    } else { // MODE 5: plain f16 row-major
        _Float16* o = (_Float16*)outp;
        #pragma unroll
        for (int m = 0; m < 4; m++) {
            #pragma unroll
            for (int n = 0; n < 4; n++) {
                const int r0 = wm * 64 + m * 16 + kg * 4;
                const int gc = bn * 128 + wn * 64 + n * 16 + lr;
                #pragma unroll
                for (int i = 0; i < 4; i++)
                    o[(size_t)(bm * 128 + r0 + i) * 1024 + gc] = (_Float16)acc[m][n][i];
            }
        }
    }
}

// ---------------- 256^2 8-phase GEMM (staggered half-slot ring, counted vmcnt) ----------------
// M0: t(f16) = xb @ W1t^T + b1                M=32768 N=1024 K=1024
// M2: gwt[b][o][m] = (xb @ W23t^T)^T  f16     M=32768 N=1024 K=1024
// M3: out(f32) = (att@gwt^T)*osc + xb@W4t^T + rsum*osc*b23 + b3 + b4  (K=512|1024)
//
// 512 thr = 8 waves (2M x 4N), per-wave C 128x64, BK=64 K-tiles, 2 ktiles/iter.
// A half-slot(kt,h) = tile rows with bit6==h; B half-slot(kt,h) = cols with bit5==h.
// Phase p (kt=p>>2, qm=(p>>1)&1, qn=p&1) reads exactly A(kt,qm), B(kt,qn).
// Slot last-read / re-stage phases: A(0,0):1/2 B(0,0):2/3 A(0,1):3/4 B(0,1):3/5
//   A(1,0):5/6 B(1,0):6/7 A(1,1):7/next-0 B(1,1):7/next-1  -> 1 half staged per phase.
// vmcnt(4) at phases 3 and 7 gates everything (proof in session log); never 0 midloop.
// LDS chunk-XOR swizzle: physical 16B chunk = logical ^ (slotline & 7).

template <int MODE>
__global__ __launch_bounds__(512) void k_gemm8(
    const _Float16* __restrict__ A0, const _Float16* __restrict__ B0,
    const _Float16* __restrict__ A1, const _Float16* __restrict__ B1,
    const float* __restrict__ biasf, const float* __restrict__ biasg,
    const float* __restrict__ auxA, const float* __restrict__ auxB,
    const float* __restrict__ sumptr, void* __restrict__ outp) {

    __shared__ _Float16 LA[32768];   // 4 slots x [128 lines][64 k]
    __shared__ _Float16 LB[32768];

    const int tid = threadIdx.x, lane = tid & 63, wid = tid >> 6;
    const int wm = wid >> 2, wn = wid & 3;
    const int lr = lane & 15, kq = lane >> 4;

    const int swz = (blockIdx.x & 7) * 64 + (blockIdx.x >> 3);
    int bm, bn, bz = 0;
    if constexpr (MODE == 3) { bz = swz >> 3; bm = (swz >> 2) & 1; bn = swz & 3; }
    else { bm = swz >> 2; bn = swz & 3; }

    constexpr int NITER = (MODE == 3) ? 12 : 8;
    float oscale = 1.f;
    if constexpr (MODE == 3) oscale = 1.f / sumptr[bz];

    const int i0 = tid >> 3;                    // slot line (low 64)
    const int kgs = (tid & 7) ^ (i0 & 7);       // staged logical k-chunk

    auto STAGE = [&](int g, int isA, int h) {
        const _Float16* P; int ld; size_t off; int kk;
        if constexpr (MODE == 3) {
            if (g < 8) {
                kk = g * 64;
                if (isA) { P = A0; ld = 512;  off = (size_t)bz * 262144 + (size_t)bm * 256 * 512; }
                else     { P = B0; ld = 512;  off = (size_t)bz * 524288 + (size_t)bn * 256 * 512; }
            } else {
                kk = (g - 8) * 64;
                if (isA) { P = A1; ld = 1024; off = ((size_t)bz * 512 + bm * 256) * 1024; }
                else     { P = B1; ld = 1024; off = (size_t)bn * 256 * 1024; }
            }
        } else {
            kk = g * 64;
            if (isA) { P = A0; ld = 1024; off = (size_t)bm * 256 * 1024; }
            else     { P = B0; ld = 1024; off = (size_t)bn * 256 * 1024; }
        }
        // line->global: A: (u>>6)*128 + h*64 + (u&63); B: (v>>5)*64 + h*32 + (v&31)
        const int l0 = isA ? (h * 64 + i0)
                           : ((i0 >> 5) * 64 + h * 32 + (i0 & 31));
        const int l1 = isA ? (128 + h * 64 + i0)
                           : (((i0 >> 5) + 2) * 64 + h * 32 + (i0 & 31));
        _Float16* dst = (isA ? LA : LB) + ((g & 1) * 2 + h) * 8192 + wid * 512;
        gload_lds16(P + off + (size_t)l0 * ld + kk + kgs * 8, dst);
        gload_lds16(P + off + (size_t)l1 * ld + kk + kgs * 8, dst + 4096);
    };

    f32x4 acc[8][4] = {};

    // prologue: ktile0 all 4 halves + ktile1 A(1,0),B(1,0)
    STAGE(0, 1, 0); STAGE(0, 0, 0); STAGE(0, 1, 1); STAGE(0, 0, 1);
    STAGE(1, 1, 0); STAGE(1, 0, 0);
    asm volatile("s_waitcnt vmcnt(4)" ::: "memory");
    __builtin_amdgcn_s_barrier();

    for (int i = 0; i < NITER; ++i) {
        if constexpr (MODE == 3) {
            if (i == 4) {   // segment A (K=512, iters 0-3) complete -> rescale
                #pragma unroll
                for (int m = 0; m < 8; m++)
                    #pragma unroll
                    for (int n = 0; n < 4; n++)
                        #pragma unroll
                        for (int v = 0; v < 4; v++) acc[m][n][v] *= oscale;
            }
        }
        const bool more = (i + 1 < NITER);
        #pragma unroll
        for (int ph = 0; ph < 8; ++ph) {
            const int kt = ph >> 2, qm = (ph >> 1) & 1, qn = ph & 1;
            const _Float16* As = LA + (kt * 2 + qm) * 8192;
            const _Float16* Bs = LB + (kt * 2 + qn) * 8192;
            f16x8 af[4][2], bf[2][2];
            #pragma unroll
            for (int j = 0; j < 4; j++)
                #pragma unroll
                for (int s = 0; s < 2; s++)
                    af[j][s] = *(const f16x8*)&As[(wm * 64 + j * 16 + lr) * 64
                                                  + ((((s << 2) | kq) ^ (lr & 7)) << 3)];
            #pragma unroll
            for (int jj = 0; jj < 2; jj++)
                #pragma unroll
                for (int s = 0; s < 2; s++)
                    bf[jj][s] = *(const f16x8*)&Bs[(wn * 32 + jj * 16 + lr) * 64
                                                   + ((((s << 2) | kq) ^ (lr & 7)) << 3)];
            // one half-tile stage per phase (schedule in header comment)
            {
                const int gadd = 1 + ((ph + 2) >> 2);          // 1,1,2,2,2,2,3,3
                const int sh = ((ph >> 1) & 1) ^ 1;            // 1,1,0,0,1,1,0,0
                const int sA = (ph & 1) ^ 1;                   // A,B,A,B,...
                if (ph < 2 || more) STAGE(2 * i + gadd, sA, sh);
            }
            __builtin_amdgcn_s_barrier();
            asm volatile("s_waitcnt lgkmcnt(0)" ::: "memory");
            __builtin_amdgcn_sched_barrier(0);
            __builtin_amdgcn_s_setprio(1);
            #pragma unroll
            for (int j = 0; j < 4; j++)
                #pragma unroll
                for (int jj = 0; jj < 2; jj++)
                    #pragma unroll
                    for (int s = 0; s < 2; s++)
                        acc[qm * 4 + j][qn * 2 + jj] = __builtin_amdgcn_mfma_f32_16x16x32_f16(
                            af[j][s], bf[jj][s], acc[qm * 4 + j][qn * 2 + jj], 0, 0, 0);
            __builtin_amdgcn_s_setprio(0);
            if (ph == 3) {
                if (more) asm volatile("s_waitcnt vmcnt(4)" ::: "memory");
                else      asm volatile("s_waitcnt vmcnt(0)" ::: "memory");
            }
            if (ph == 7 && more) asm volatile("s_waitcnt vmcnt(4)" ::: "memory");
            __builtin_amdgcn_s_barrier();
        }
    }

    // ---------------- epilogues ----------------
    #pragma unroll
    for (int m = 0; m < 8; m++) {
        #pragma unroll
        for (int n = 0; n < 4; n++) {
            const int gc = bn * 256 + wn * 64 + n * 16 + lr;
            const int gr0 = bm * 256 + wm * 128 + m * 16 + kq * 4;
            if constexpr (MODE == 0) {
                _Float16* o = (_Float16*)outp;
                const float bias = biasf[gc];
                #pragma unroll
                for (int i = 0; i < 4; i++)
                    o[(size_t)(gr0 + i) * 1024 + gc] = (_Float16)(acc[m][n][i] + bias);
            } else if constexpr (MODE == 2) {
                _Float16* o = (_Float16*)outp;
                const int bb = gr0 >> 9, mm = gr0 & 511;
                f16x4 pk;
                #pragma unroll
                for (int i = 0; i < 4; i++) pk[i] = (_Float16)acc[m][n][i];
                *(f16x4*)(o + ((size_t)bb * 1024 + gc) * 512 + mm) = pk;
            } else { // MODE 3
                float* o = (float*)outp;
                const float tail = biasf[gc] + biasg[gc];
                const float b23v = auxB[gc];
                #pragma unroll
                for (int i = 0; i < 4; i++) {
                    const int row = gr0 + i;   // 0..511
                    o[((size_t)bz * 512 + row) * 1024 + gc] =
                        acc[m][n][i] + auxA[bz * 512 + row] * oscale * b23v + tail;
                }
            }
        }
    }
}

// ---------------- launcher ----------------

extern "C" void kernel_launch(void* const* d_in, const int* in_sizes, int n_in,
                              void* d_out, int out_size, void* d_ws, size_t ws_size,
                              hipStream_t stream) {
    (void)in_sizes; (void)n_in; (void)out_size; (void)ws_size;
    const float* x     = (const float*)d_in[0];
    const float* W1    = (const float*)d_in[1];
    const float* b1    = (const float*)d_in[2];
    const float* gamma = (const float*)d_in[3];
    const float* beta  = (const float*)d_in[4];
    const float* W2    = (const float*)d_in[5];
    const float* b2    = (const float*)d_in[6];
    const float* W3    = (const float*)d_in[7];
    const float* b3    = (const float*)d_in[8];
    const float* W4    = (const float*)d_in[9];
    const float* b4    = (const float*)d_in[10];

    char* wsb = (char*)d_ws;
    const size_t MB = 1024 * 1024;
    _Float16* xb    = (_Float16*)(wsb);                   // 64 MB
    _Float16* W1t   = (_Float16*)(wsb + 64 * MB);
    _Float16* W3t   = (_Float16*)(wsb + 66 * MB);
    _Float16* W4t   = (_Float16*)(wsb + 68 * MB);
    _Float16* W2h   = (_Float16*)(wsb + 70 * MB);
    _Float16* W23t  = (_Float16*)(wsb + 72 * MB);
    float*    b23   = (float*)(wsb + 74 * MB);            // 4 KB
    float*    scl   = (float*)(wsb + 74 * MB + 8192);
    float*    shf   = (float*)(wsb + 74 * MB + 16384);
    float*    ssum  = (float*)(wsb + 74 * MB + 24576);
    float*    mu    = (float*)(wsb + 75 * MB);            // 128 KB
    float*    rsum  = (float*)(wsb + 76 * MB);            // 128 KB
    float*    rpart = (float*)(wsb + 77 * MB);            // 512 KB
    _Float16* t     = (_Float16*)(wsb + 80 * MB);         // 64 MB
    _Float16* theta = (_Float16*)(wsb + 144 * MB);        // 64 MB
    _Float16* att   = (_Float16*)(wsb + 208 * MB);        // 32 MB
    _Float16* gwt   = (_Float16*)(wsb + 240 * MB);        // 64 MB

    // prep
    k_cvt_f16<<<8192, 256, 0, stream>>>(x, xb, 64 * 512 * 1024 / 4);
    k_cvt_f16<<<1024, 256, 0, stream>>>(W2, W2h, 1024 * 1024 / 4);
    dim3 tb(32, 8), tg(32, 32);
    k_transpose_w<<<tg, tb, 0, stream>>>(W1, W1t);
    k_transpose_w<<<tg, tb, 0, stream>>>(W3, W3t);
    k_transpose_w<<<tg, tb, 0, stream>>>(W4, W4t);
    // W23t = (W2@W3)^T
    k_gemm<5><<<dim3(8, 8, 1), 256, 0, stream>>>(W3t, W2h, nullptr, nullptr, W23t);
    k_b23<<<16, 256, 0, stream>>>(b2, W3, b23);
    // t = xb @ W1 + b1 (f16)  [8-phase]
    k_gemm8<0><<<512, 512, 0, stream>>>(xb, W1t, nullptr, nullptr,
        b1, nullptr, nullptr, nullptr, nullptr, t);
    // BN stats + normalize
    k_bnstats<<<512, 256, 0, stream>>>(t, gamma, beta, scl, shf);
    k_bnorm<<<32768, 256, 0, stream>>>(t, scl, shf, theta, mu);
    // att = exp(sigma) + per-block row partials
    k_gemm<1><<<dim3(4, 4, 64), 256, 0, stream>>>(theta, theta, mu, rpart, att);
    // rsum / ssum
    k_ssum<<<64, 512, 0, stream>>>(rpart, rsum, ssum);
    // gwt = (xb @ W23)^T per batch [b][o][m]  [8-phase]
    k_gemm8<2><<<512, 512, 0, stream>>>(xb, W23t, nullptr, nullptr,
        nullptr, nullptr, nullptr, nullptr, nullptr, gwt);
    // out = att@gwt*osc + xb@W4 + rsum*osc*b23 + b3 + b4  [8-phase]
    k_gemm8<3><<<512, 512, 0, stream>>>(att, gwt, xb, W4t,
        b3, b4, rsum, b23, ssum, d_out);
}

// Round 8
// 463.189 us; speedup vs baseline: 2.4407x; 1.0865x over previous
//
#include <hip/hip_runtime.h>
#include <hip/hip_bf16.h>

typedef _Float16 f16x8 __attribute__((ext_vector_type(8)));
typedef _Float16 f16x4 __attribute__((ext_vector_type(4)));
typedef float    f32x4 __attribute__((ext_vector_type(4)));

#define EPS_ 1e-5f

__device__ __forceinline__ void gload_lds16(const _Float16* g, _Float16* l) {
    __builtin_amdgcn_global_load_lds(
        (const __attribute__((address_space(1))) void*)g,
        (__attribute__((address_space(3))) void*)l, 16, 0, 0);
}

// ---------------- elementwise / prep kernels ----------------

__global__ void k_cvt_f16(const float* __restrict__ in, _Float16* __restrict__ out, int n4) {
    int i = blockIdx.x * blockDim.x + threadIdx.x;
    int stride = gridDim.x * blockDim.x;
    const float4* in4 = (const float4*)in;
    for (; i < n4; i += stride) {
        float4 v = in4[i];
        f16x4 o;
        o[0] = (_Float16)v.x; o[1] = (_Float16)v.y;
        o[2] = (_Float16)v.z; o[3] = (_Float16)v.w;
        *(f16x4*)(out + (size_t)i * 4) = o;
    }
}

// W [1024][1024] fp32 -> Wt [1024][1024] f16 (transposed)
__global__ void k_transpose_w(const float* __restrict__ in, _Float16* __restrict__ out) {
    __shared__ float tile[32][33];
    int bx = blockIdx.x * 32;
    int by = blockIdx.y * 32;
    int tx = threadIdx.x, ty = threadIdx.y;
    #pragma unroll
    for (int r = 0; r < 32; r += 8)
        tile[ty + r][tx] = in[(size_t)(by + ty + r) * 1024 + bx + tx];
    __syncthreads();
    #pragma unroll
    for (int r = 0; r < 32; r += 8)
        out[(size_t)(bx + ty + r) * 1024 + by + tx] = (_Float16)tile[tx][ty + r];
}

// b23[o] = sum_h b2[h] * W3[h][o]
__global__ void k_b23(const float* __restrict__ b2, const float* __restrict__ W3,
                      float* __restrict__ b23) {
    const int oo = threadIdx.x & 63, hc = threadIdx.x >> 6;
    const int o = blockIdx.x * 64 + oo;
    float s = 0.f;
    for (int h = hc * 256; h < hc * 256 + 256; ++h) s += b2[h] * W3[(size_t)h * 1024 + o];
    __shared__ float red[4][64];
    red[hc][oo] = s;
    __syncthreads();
    if (threadIdx.x < 64) {
        int o2 = blockIdx.x * 64 + threadIdx.x;
        b23[o2] = red[0][threadIdx.x] + red[1][threadIdx.x] + red[2][threadIdx.x] + red[3][threadIdx.x];
    }
}

// ---------------- BN stats / normalize (t in f16) ----------------

__global__ void k_bnstats(const _Float16* __restrict__ t, const float* __restrict__ gamma,
                          const float* __restrict__ beta, float* __restrict__ scale,
                          float* __restrict__ shift) {
    const int n = blockIdx.x, tid = threadIdx.x;
    float s = 0.f, s2 = 0.f;
    const _Float16* base = t + (size_t)n * 1024 + tid * 4;
    for (int b = 0; b < 64; ++b) {
        f16x4 v = *(const f16x4*)(base + (size_t)b * 512 * 1024);
        float x0 = (float)v[0], x1 = (float)v[1], x2 = (float)v[2], x3 = (float)v[3];
        s  += x0 + x1 + x2 + x3;
        s2 += x0 * x0 + x1 * x1 + x2 * x2 + x3 * x3;
    }
    #pragma unroll
    for (int o = 32; o > 0; o >>= 1) { s += __shfl_down(s, o); s2 += __shfl_down(s2, o); }
    __shared__ float rs_[4], rs2_[4];
    int lane = tid & 63, w = tid >> 6;
    if (lane == 0) { rs_[w] = s; rs2_[w] = s2; }
    __syncthreads();
    if (tid == 0) {
        float S  = rs_[0] + rs_[1] + rs_[2] + rs_[3];
        float S2 = rs2_[0] + rs2_[1] + rs2_[2] + rs2_[3];
        float mean = S * (1.f / 65536.f);
        float var  = S2 * (1.f / 65536.f) - mean * mean;
        float r = rsqrtf(var + EPS_);
        float sc = gamma[n] * r;
        scale[n] = sc;
        shift[n] = beta[n] - mean * sc;
    }
}

// normalize + leaky, write theta f16 and row-mean mu
__global__ void k_bnorm(const _Float16* __restrict__ t, const float* __restrict__ scale,
                        const float* __restrict__ shift, _Float16* __restrict__ theta,
                        float* __restrict__ mu) {
    const int row = blockIdx.x, tid = threadIdx.x;
    const int n = row & 511;
    const float sc = scale[n], sh = shift[n];
    f16x4 v = *(const f16x4*)(t + (size_t)row * 1024 + tid * 4);
    float a0 = fmaf((float)v[0], sc, sh); a0 = a0 >= 0.f ? a0 : 0.01f * a0;
    float a1 = fmaf((float)v[1], sc, sh); a1 = a1 >= 0.f ? a1 : 0.01f * a1;
    float a2 = fmaf((float)v[2], sc, sh); a2 = a2 >= 0.f ? a2 : 0.01f * a2;
    float a3 = fmaf((float)v[3], sc, sh); a3 = a3 >= 0.f ? a3 : 0.01f * a3;
    float s = a0 + a1 + a2 + a3;
    #pragma unroll
    for (int o = 32; o > 0; o >>= 1) s += __shfl_down(s, o);
    __shared__ float red[4];
    int lane = tid & 63, w = tid >> 6;
    if (lane == 0) red[w] = s;
    __syncthreads();
    const float mean = (red[0] + red[1] + red[2] + red[3]) * (1.f / 1024.f);
    f16x4 th;
    th[0] = (_Float16)a0; th[1] = (_Float16)a1; th[2] = (_Float16)a2; th[3] = (_Float16)a3;
    *(f16x4*)(theta + (size_t)row * 1024 + tid * 4) = th;
    if (tid == 0) mu[row] = mean;
}

// rsum[b][j] = sum_bn part[bn][b][j]; ssum[b] = sum_j rsum[b][j]
__global__ void k_ssum(const float* __restrict__ part, float* __restrict__ rsum,
                       float* __restrict__ ssum) {
    const int b = blockIdx.x, j = threadIdx.x;   // 512 threads
    const int idx = b * 512 + j;
    float s = part[idx] + part[32768 + idx] + part[65536 + idx] + part[98304 + idx];
    rsum[idx] = s;
    #pragma unroll
    for (int o = 32; o > 0; o >>= 1) s += __shfl_down(s, o);
    __shared__ float red[8];
    if ((j & 63) == 0) red[j >> 6] = s;
    __syncthreads();
    if (j == 0) {
        float tt = 0.f;
        #pragma unroll
        for (int k = 0; k < 8; k++) tt += red[k];
        ssum[b] = tt;
    }
}

// ---------------- old 128^2 GEMM (kept for MODE 1 [sigma+exp] and MODE 5) ----------------

template <int MODE>
__global__ __launch_bounds__(256) void k_gemm(
    const _Float16* __restrict__ A0, const _Float16* __restrict__ B0,
    const float* __restrict__ auxA, float* __restrict__ auxW,
    void* __restrict__ outp) {

    constexpr int BK = 32;
    __shared__ _Float16 Al[4096];
    __shared__ _Float16 Bl[4096];

    const int tid = threadIdx.x, lane = tid & 63, w = tid >> 6;
    const int wm = w >> 1, wn = w & 1;
    const int bm = blockIdx.x, bn = blockIdx.y, bz = blockIdx.z;

    const int srow = tid >> 2;
    const int skofs = ((tid & 3) ^ ((tid >> 3) & 3)) * 8;
    _Float16* lA0 = &Al[(w * 64) * 8];
    _Float16* lA1 = &Al[(256 + w * 64) * 8];
    _Float16* lB0 = &Bl[(w * 64) * 8];
    _Float16* lB1 = &Bl[(256 + w * 64) * 8];

    const int lr = lane & 15, kg = lane >> 4;
    const int kswz = kg ^ ((lr >> 1) & 3);

    f32x4 acc[4][4] = {};

    const size_t aO = ((size_t)bz * 512 + bm * 128) * 1024;
    const size_t bO = ((size_t)bz * 512 + bn * 128) * 1024;
    for (int k0 = 0; k0 < 1024; k0 += BK) {
        gload_lds16(A0 + aO + (size_t)srow * 1024 + k0 + skofs, lA0);
        gload_lds16(A0 + aO + (size_t)(srow + 64) * 1024 + k0 + skofs, lA1);
        gload_lds16(B0 + bO + (size_t)srow * 1024 + k0 + skofs, lB0);
        gload_lds16(B0 + bO + (size_t)(srow + 64) * 1024 + k0 + skofs, lB1);
        __syncthreads();
        f16x8 af[4], bf[4];
        #pragma unroll
        for (int m = 0; m < 4; m++)
            af[m] = *(const f16x8*)&Al[((wm * 64 + m * 16 + lr) * 4 + kswz) * 8];
        #pragma unroll
        for (int n = 0; n < 4; n++)
            bf[n] = *(const f16x8*)&Bl[((wn * 64 + n * 16 + lr) * 4 + kswz) * 8];
        #pragma unroll
        for (int m = 0; m < 4; m++)
            #pragma unroll
            for (int n = 0; n < 4; n++)
                acc[m][n] = __builtin_amdgcn_mfma_f32_16x16x32_f16(af[m], bf[n], acc[m][n], 0, 0, 0);
        __syncthreads();
    }

    if constexpr (MODE == 1) {
        __shared__ float rbuf[2][128];
        _Float16* o = (_Float16*)outp + (size_t)bz * 262144;
        #pragma unroll
        for (int m = 0; m < 4; m++) {
            const int r0 = wm * 64 + m * 16 + kg * 4;
            float rs[4] = {0.f, 0.f, 0.f, 0.f};
            #pragma unroll
            for (int n = 0; n < 4; n++) {
                const int gc = bn * 128 + wn * 64 + n * 16 + lr;
                const float mj = auxA[bz * 512 + gc];
                #pragma unroll
                for (int i = 0; i < 4; i++) {
                    const float mi = auxA[bz * 512 + bm * 128 + r0 + i];
                    const float e = __expf(acc[m][n][i] * (1.f / 32768.f) - mi * mj * (1.f / 32.f));
                    o[(size_t)(bm * 128 + r0 + i) * 512 + gc] = (_Float16)e;
                    rs[i] += e;
                }
            }
            #pragma unroll
            for (int i = 0; i < 4; i++) {
                float v = rs[i];
                v += __shfl_xor(v, 1); v += __shfl_xor(v, 2);
                v += __shfl_xor(v, 4); v += __shfl_xor(v, 8);
                if (lr == 0) rbuf[wn][r0 + i] = v;
            }
        }
        __syncthreads();
        if (tid < 128)
            auxW[(size_t)bn * 32768 + bz * 512 + bm * 128 + tid] = rbuf[0][tid] + rbuf[1][tid];
    } else { // MODE 5: plain f16 row-major
        _Float16* o = (_Float16*)outp;
        #pragma unroll
        for (int m = 0; m < 4; m++) {
            #pragma unroll
            for (int n = 0; n < 4; n++) {
                const int r0 = wm * 64 + m * 16 + kg * 4;
                const int gc = bn * 128 + wn * 64 + n * 16 + lr;
                #pragma unroll
                for (int i = 0; i < 4; i++)
                    o[(size_t)(bm * 128 + r0 + i) * 1024 + gc] = (_Float16)acc[m][n][i];
            }
        }
    }
}

// ---------------- 256^2 8-phase GEMM, minimal-LDS-traffic phases ----------------
// M0: t(f16) = xb @ W1t^T + b1                M=32768 N=1024 K=1024
// M2: gwt[b][o][m] = (xb @ W23t^T)^T  f16     M=32768 N=1024 K=1024
// M3: out(f32) = (att@gwt^T)*osc + xb@W4t^T + rsum*osc*b23 + b3 + b4  (K=512|1024)
//
// 512 thr = 8 waves (2M x 4N), per-wave C 128x64, BK=64, 2 k-tiles/iter, 8 phases.
// Per k-tile: sub0 reads ALL B frags (8 ds_read, held in regs for 4 phases) +
// A m-pair0 (4 reads); sub1/2/3 read A m-pairs (4 reads each) -> 48 reads/iter
// = minimal fragment traffic (was 96 with quadrant phases -> LDS-read-bound).
// Stage map/phase: {A(2i+1,1), B(2i+2,0), B(2i+2,1), A(2i+2,0), A(2i+2,1),
//                   B(2i+3,0), B(2i+3,1), A(2i+3,0)}; waits vmcnt 10/8/10/8 at
// ph1/3/5/7 (tail 8/2/0/-). Steady state 14->8 outstanding; every slot staged
// >= lastread+1 phase; every load lands >= 4 phases before first read.

template <int MODE>
__global__ __launch_bounds__(512) void k_gemm8(
    const _Float16* __restrict__ A0, const _Float16* __restrict__ B0,
    const _Float16* __restrict__ A1, const _Float16* __restrict__ B1,
    const float* __restrict__ biasf, const float* __restrict__ biasg,
    const float* __restrict__ auxA, const float* __restrict__ auxB,
    const float* __restrict__ sumptr, void* __restrict__ outp) {

    __shared__ _Float16 LA[32768];   // 4 half-slots x [128 lines][64 k]
    __shared__ _Float16 LB[32768];

    const int tid = threadIdx.x, lane = tid & 63, wid = tid >> 6;
    const int wm = wid >> 2, wn = wid & 3;
    const int lr = lane & 15, kq = lane >> 4;

    const int swz = (blockIdx.x & 7) * 64 + (blockIdx.x >> 3);
    int bm, bn, bz = 0;
    if constexpr (MODE == 3) { bz = swz >> 3; bm = (swz >> 2) & 1; bn = swz & 3; }
    else { bm = swz >> 2; bn = swz & 3; }

    constexpr int NITER = (MODE == 3) ? 12 : 8;
    float oscale = 1.f;
    if constexpr (MODE == 3) oscale = 1.f / sumptr[bz];

    const int i0 = tid >> 3;                    // slot line (low 64)
    const int kgs = (tid & 7) ^ (i0 & 7);       // staged logical k-chunk

    auto STAGE = [&](int g, int isA, int h) {
        const _Float16* P; int ld; size_t off; int kk;
        if constexpr (MODE == 3) {
            if (g < 8) {
                kk = g * 64;
                if (isA) { P = A0; ld = 512;  off = (size_t)bz * 262144 + (size_t)bm * 256 * 512; }
                else     { P = B0; ld = 512;  off = (size_t)bz * 524288 + (size_t)bn * 256 * 512; }
            } else {
                kk = (g - 8) * 64;
                if (isA) { P = A1; ld = 1024; off = ((size_t)bz * 512 + bm * 256) * 1024; }
                else     { P = B1; ld = 1024; off = (size_t)bn * 256 * 1024; }
            }
        } else {
            kk = g * 64;
            if (isA) { P = A0; ld = 1024; off = (size_t)bm * 256 * 1024; }
            else     { P = B0; ld = 1024; off = (size_t)bn * 256 * 1024; }
        }
        const int l0 = isA ? (h * 64 + i0)
                           : ((i0 >> 5) * 64 + h * 32 + (i0 & 31));
        const int l1 = isA ? (128 + h * 64 + i0)
                           : (((i0 >> 5) + 2) * 64 + h * 32 + (i0 & 31));
        _Float16* dst = (isA ? LA : LB) + ((g & 1) * 2 + h) * 8192 + wid * 512;
        gload_lds16(P + off + (size_t)l0 * ld + kk + kgs * 8, dst);
        gload_lds16(P + off + (size_t)l1 * ld + kk + kgs * 8, dst + 4096);
    };

    f32x4 acc[8][4] = {};

    // prologue: k-tile0 (A h0, B h0, B h1, A h1) then B(1,0), B(1,1), A(1,0)
    STAGE(0, 1, 0); STAGE(0, 0, 0); STAGE(0, 0, 1); STAGE(0, 1, 1);
    STAGE(1, 0, 0); STAGE(1, 0, 1); STAGE(1, 1, 0);
    asm volatile("s_waitcnt vmcnt(6)" ::: "memory");
    __builtin_amdgcn_s_barrier();

    for (int i = 0; i < NITER; ++i) {
        if constexpr (MODE == 3) {
            if (i == 4) {   // segment A (K=512, iters 0-3) complete -> rescale
                #pragma unroll
                for (int m = 0; m < 8; m++)
                    #pragma unroll
                    for (int n = 0; n < 4; n++)
                        #pragma unroll
                        for (int v = 0; v < 4; v++) acc[m][n][v] *= oscale;
            }
        }
        const bool more = (i + 1 < NITER);
        #pragma unroll
        for (int kt = 0; kt < 2; ++kt) {
            f16x8 bf[4][2];           // all B fragments of this k-tile, live 4 phases
            #pragma unroll
            for (int sub = 0; sub < 4; ++sub) {
                const int ph = kt * 4 + sub;
                // --- ds reads ---
                if (sub == 0) {
                    #pragma unroll
                    for (int n = 0; n < 4; n++) {
                        const _Float16* Bs = LB + (kt * 2 + (n >> 1)) * 8192;
                        #pragma unroll
                        for (int s = 0; s < 2; s++)
                            bf[n][s] = *(const f16x8*)&Bs[(wn * 32 + (n & 1) * 16 + lr) * 64
                                                           + ((((s << 2) | kq) ^ (lr & 7)) << 3)];
                    }
                }
                const _Float16* As = LA + (kt * 2 + (sub >> 1)) * 8192;
                f16x8 af[2][2];
                #pragma unroll
                for (int j = 0; j < 2; j++) {
                    const int m = sub * 2 + j;
                    #pragma unroll
                    for (int s = 0; s < 2; s++)
                        af[j][s] = *(const f16x8*)&As[(wm * 64 + (m & 3) * 16 + lr) * 64
                                                       + ((((s << 2) | kq) ^ (lr & 7)) << 3)];
                }
                // --- stage issue (map in header comment) ---
                {
                    constexpr int gof[8] = {1, 2, 2, 2, 2, 3, 3, 3};
                    constexpr int isa[8] = {1, 0, 0, 1, 1, 0, 0, 1};
                    constexpr int hh [8] = {1, 0, 1, 0, 1, 0, 1, 0};
                    if (ph == 0 || more) STAGE(2 * i + gof[ph], isa[ph], hh[ph]);
                }
                __builtin_amdgcn_s_barrier();
                asm volatile("s_waitcnt lgkmcnt(0)" ::: "memory");
                __builtin_amdgcn_sched_barrier(0);
                __builtin_amdgcn_s_setprio(1);
                #pragma unroll
                for (int j = 0; j < 2; j++)
                    #pragma unroll
                    for (int n = 0; n < 4; n++)
                        #pragma unroll
                        for (int s = 0; s < 2; s++)
                            acc[sub * 2 + j][n] = __builtin_amdgcn_mfma_f32_16x16x32_f16(
                                af[j][s], bf[n][s], acc[sub * 2 + j][n], 0, 0, 0);
                __builtin_amdgcn_s_setprio(0);
                if (ph == 1) { if (more) asm volatile("s_waitcnt vmcnt(10)" ::: "memory");
                               else      asm volatile("s_waitcnt vmcnt(8)"  ::: "memory"); }
                if (ph == 3) { if (more) asm volatile("s_waitcnt vmcnt(8)"  ::: "memory");
                               else      asm volatile("s_waitcnt vmcnt(2)"  ::: "memory"); }
                if (ph == 5) { if (more) asm volatile("s_waitcnt vmcnt(10)" ::: "memory");
                               else      asm volatile("s_waitcnt vmcnt(0)"  ::: "memory"); }
                if (ph == 7) { if (more) asm volatile("s_waitcnt vmcnt(8)"  ::: "memory"); }
                __builtin_amdgcn_s_barrier();
            }
        }
    }

    // ---------------- epilogues ----------------
    #pragma unroll
    for (int m = 0; m < 8; m++) {
        #pragma unroll
        for (int n = 0; n < 4; n++) {
            const int gc = bn * 256 + wn * 64 + n * 16 + lr;
            const int gr0 = bm * 256 + wm * 128 + m * 16 + kq * 4;
            if constexpr (MODE == 0) {
                _Float16* o = (_Float16*)outp;
                const float bias = biasf[gc];
                #pragma unroll
                for (int i = 0; i < 4; i++)
                    o[(size_t)(gr0 + i) * 1024 + gc] = (_Float16)(acc[m][n][i] + bias);
            } else if constexpr (MODE == 2) {
                _Float16* o = (_Float16*)outp;
                const int bb = gr0 >> 9, mm = gr0 & 511;
                f16x4 pk;
                #pragma unroll
                for (int i = 0; i < 4; i++) pk[i] = (_Float16)acc[m][n][i];
                *(f16x4*)(o + ((size_t)bb * 1024 + gc) * 512 + mm) = pk;
            } else { // MODE 3
                float* o = (float*)outp;
                const float tail = biasf[gc] + biasg[gc];
                const float b23v = auxB[gc];
                #pragma unroll
                for (int i = 0; i < 4; i++) {
                    const int row = gr0 + i;   // 0..511
                    o[((size_t)bz * 512 + row) * 1024 + gc] =
                        acc[m][n][i] + auxA[bz * 512 + row] * oscale * b23v + tail;
                }
            }
        }
    }
}

// ---------------- launcher ----------------

extern "C" void kernel_launch(void* const* d_in, const int* in_sizes, int n_in,
                              void* d_out, int out_size, void* d_ws, size_t ws_size,
                              hipStream_t stream) {
    (void)in_sizes; (void)n_in; (void)out_size; (void)ws_size;
    const float* x     = (const float*)d_in[0];
    const float* W1    = (const float*)d_in[1];
    const float* b1    = (const float*)d_in[2];
    const float* gamma = (const float*)d_in[3];
    const float* beta  = (const float*)d_in[4];
    const float* W2    = (const float*)d_in[5];
    const float* b2    = (const float*)d_in[6];
    const float* W3    = (const float*)d_in[7];
    const float* b3    = (const float*)d_in[8];
    const float* W4    = (const float*)d_in[9];
    const float* b4    = (const float*)d_in[10];

    char* wsb = (char*)d_ws;
    const size_t MB = 1024 * 1024;
    _Float16* xb    = (_Float16*)(wsb);                   // 64 MB
    _Float16* W1t   = (_Float16*)(wsb + 64 * MB);
    _Float16* W3t   = (_Float16*)(wsb + 66 * MB);
    _Float16* W4t   = (_Float16*)(wsb + 68 * MB);
    _Float16* W2h   = (_Float16*)(wsb + 70 * MB);
    _Float16* W23t  = (_Float16*)(wsb + 72 * MB);
    float*    b23   = (float*)(wsb + 74 * MB);            // 4 KB
    float*    scl   = (float*)(wsb + 74 * MB + 8192);
    float*    shf   = (float*)(wsb + 74 * MB + 16384);
    float*    ssum  = (float*)(wsb + 74 * MB + 24576);
    float*    mu    = (float*)(wsb + 75 * MB);            // 128 KB
    float*    rsum  = (float*)(wsb + 76 * MB);            // 128 KB
    float*    rpart = (float*)(wsb + 77 * MB);            // 512 KB
    _Float16* t     = (_Float16*)(wsb + 80 * MB);         // 64 MB
    _Float16* theta = (_Float16*)(wsb + 144 * MB);        // 64 MB
    _Float16* att   = (_Float16*)(wsb + 208 * MB);        // 32 MB
    _Float16* gwt   = (_Float16*)(wsb + 240 * MB);        // 64 MB

    // prep
    k_cvt_f16<<<8192, 256, 0, stream>>>(x, xb, 64 * 512 * 1024 / 4);
    k_cvt_f16<<<1024, 256, 0, stream>>>(W2, W2h, 1024 * 1024 / 4);
    dim3 tb(32, 8), tg(32, 32);
    k_transpose_w<<<tg, tb, 0, stream>>>(W1, W1t);
    k_transpose_w<<<tg, tb, 0, stream>>>(W3, W3t);
    k_transpose_w<<<tg, tb, 0, stream>>>(W4, W4t);
    // W23t = (W2@W3)^T
    k_gemm<5><<<dim3(8, 8, 1), 256, 0, stream>>>(W3t, W2h, nullptr, nullptr, W23t);
    k_b23<<<16, 256, 0, stream>>>(b2, W3, b23);
    // t = xb @ W1 + b1 (f16)  [8-phase minimal-traffic]
    k_gemm8<0><<<512, 512, 0, stream>>>(xb, W1t, nullptr, nullptr,
        b1, nullptr, nullptr, nullptr, nullptr, t);
    // BN stats + normalize
    k_bnstats<<<512, 256, 0, stream>>>(t, gamma, beta, scl, shf);
    k_bnorm<<<32768, 256, 0, stream>>>(t, scl, shf, theta, mu);
    // att = exp(sigma) + per-block row partials
    k_gemm<1><<<dim3(4, 4, 64), 256, 0, stream>>>(theta, theta, mu, rpart, att);
    // rsum / ssum
    k_ssum<<<64, 512, 0, stream>>>(rpart, rsum, ssum);
    // gwt = (xb @ W23)^T per batch [b][o][m]  [8-phase minimal-traffic]
    k_gemm8<2><<<512, 512, 0, stream>>>(xb, W23t, nullptr, nullptr,
        nullptr, nullptr, nullptr, nullptr, nullptr, gwt);
    // out = att@gwt*osc + xb@W4 + rsum*osc*b23 + b3 + b4  [8-phase minimal-traffic]
    k_gemm8<3><<<512, 512, 0, stream>>>(att, gwt, xb, W4t,
        b3, b4, rsum, b23, ssum, d_out);
}